// Round 1
// baseline (285.888 us; speedup 1.0000x reference)
//
#include <hip/hip_runtime.h>

// LinearAttention, fp16-MFMA restructuring (round 4).
//   xT   = transpose+cvt(x)          [b][l][c] f16   (B-operand for K1,K5)
//   kv   = wkvT @ xT^T  (MFMA)       [b][f][l] f16, f<512:k, f>=512:v
//   k    = softmax_L(k)              in place, f16
//   ctxP = v k^T partials (MFMA, K split 16)  [s][bh][e*64+d] f32
//   a2tT = (sum_s ctxP . w_out)^T    [b][c][g] f16  (k-fast for M-build)
//   Mf   = a2tT @ wqs^T (MFMA)       [b][c][c'] f16 = A-operand of K5
//   out  = Mf @ xT^T + b_out (MFMA, fp32 out)
// q never materialized (linear in x, folded into Mf).
// Round-4 change: gemm_mfma/context_mfma K-loops converted from
// {barrier; stage; drain; compute} to T3 2-phase double-buffered pipeline:
// {stage next (static dbuf names); compute current; vmcnt(0); s_barrier}.
// Load latency now hides under MFMA instead of preceding it.

typedef _Float16 half2_t __attribute__((ext_vector_type(2)));
typedef _Float16 half4_t __attribute__((ext_vector_type(4)));
typedef _Float16 half8_t __attribute__((ext_vector_type(8)));
typedef float    floatx4 __attribute__((ext_vector_type(4)));

#define SCALE_ 0.125f
#define CSPLIT 16

__device__ __forceinline__ void async_lds16(const _Float16* g, _Float16* l) {
    __builtin_amdgcn_global_load_lds(
        (const __attribute__((address_space(1))) void*)g,
        (__attribute__((address_space(3))) void*)l,
        16, 0, 0);
}

#define WAIT_VM0_BARRIER() do { \
    asm volatile("s_waitcnt vmcnt(0)" ::: "memory"); \
    __builtin_amdgcn_s_barrier(); \
    asm volatile("" ::: "memory"); \
} while (0)

// ---------------- MFMA GEMM: C[m][n] = sum_k A[m][k] * B[n][k] (+bias[m]) ---
// A: [M][K] f16 k-fast (lda=K). B: [N][K] f16 k-fast (ldb=K). C: [M][N].
// 128x128 tile, BK=32, 4 waves, 16x16x32_f16, global_load_lds width 16.
// 2-phase double-buffered pipeline (T3 minimal recipe), static buffer names.
template <typename OutT>
__global__ __launch_bounds__(256)
void gemm_mfma(const _Float16* __restrict__ A, long aBatch, int K,
               const _Float16* __restrict__ B, long bBatch,
               OutT* __restrict__ C, int ldc, long cBatch,
               const float* __restrict__ bias)
{
    __shared__ _Float16 As0[128 * 32];
    __shared__ _Float16 As1[128 * 32];
    __shared__ _Float16 Bs0[128 * 32];
    __shared__ _Float16 Bs1[128 * 32];
    const int tid  = threadIdx.x;
    const int lane = tid & 63;
    const int wave = tid >> 6;
    const int m0 = blockIdx.y * 128;
    const int n0 = blockIdx.x * 128;
    const long bz = blockIdx.z;

    // staging map: thread t -> row t>>2 (64 rows/issue), 16B chunk t&3
    const int sr = tid >> 2;
    const int sc = (tid & 3) * 8;
    const _Float16* Ag = A + bz * aBatch + (long)(m0 + sr) * K + sc;
    const _Float16* Bg = B + bz * bBatch + (long)(n0 + sr) * K + sc;

    const int wm = (wave & 1) * 64;
    const int wn = (wave >> 1) * 64;
    const int fm = lane & 15;          // fragment m / n
    const int fk = (lane >> 4) * 8;    // fragment k offset (elems)

    floatx4 acc[4][4];
#pragma unroll
    for (int i = 0; i < 4; ++i)
#pragma unroll
        for (int j = 0; j < 4; ++j) acc[i][j] = (floatx4)0.0f;

#define STAGE_G(AS, BS, K0) do { \
    async_lds16(Ag + (K0),                 &AS[tid * 8]); \
    async_lds16(Ag + 64 * (long)K + (K0),  &AS[2048 + tid * 8]); \
    async_lds16(Bg + (K0),                 &BS[tid * 8]); \
    async_lds16(Bg + 64 * (long)K + (K0),  &BS[2048 + tid * 8]); \
} while (0)

#define COMPUTE_G(AS, BS) do { \
    half8_t a_[4], b_[4]; \
    _Pragma("unroll") \
    for (int i = 0; i < 4; ++i) \
        a_[i] = *(const half8_t*)&AS[(wm + i * 16 + fm) * 32 + fk]; \
    _Pragma("unroll") \
    for (int j = 0; j < 4; ++j) \
        b_[j] = *(const half8_t*)&BS[(wn + j * 16 + fm) * 32 + fk]; \
    __builtin_amdgcn_s_setprio(1); \
    _Pragma("unroll") \
    for (int i = 0; i < 4; ++i) \
    _Pragma("unroll") \
        for (int j = 0; j < 4; ++j) \
            acc[i][j] = __builtin_amdgcn_mfma_f32_16x16x32_f16( \
                a_[i], b_[j], acc[i][j], 0, 0, 0); \
    __builtin_amdgcn_s_setprio(0); \
} while (0)

    // prologue: fill buffer 0
    STAGE_G(As0, Bs0, 0);
    WAIT_VM0_BARRIER();

    int k0 = 0;
    while (true) {
        // phase A: prefetch -> buf1, compute buf0
        if (k0 + 32 < K) STAGE_G(As1, Bs1, k0 + 32);
        COMPUTE_G(As0, Bs0);
        WAIT_VM0_BARRIER();
        k0 += 32;
        if (k0 >= K) break;
        // phase B: prefetch -> buf0, compute buf1
        if (k0 + 32 < K) STAGE_G(As0, Bs0, k0 + 32);
        COMPUTE_G(As1, Bs1);
        WAIT_VM0_BARRIER();
        k0 += 32;
        if (k0 >= K) break;
    }
#undef STAGE_G
#undef COMPUTE_G

    // C/D layout: n = lane&15, m = (lane>>4)*4 + reg   [m89/m91-verified]
    const int em = (lane >> 4) * 4;
    const int en = lane & 15;
    OutT* Cb = C + bz * cBatch;
#pragma unroll
    for (int i = 0; i < 4; ++i) {
#pragma unroll
        for (int r = 0; r < 4; ++r) {
            const int m = m0 + wm + i * 16 + em + r;
            const float bi = bias ? bias[m] : 0.0f;
#pragma unroll
            for (int j = 0; j < 4; ++j) {
                const int n = n0 + wn + j * 16 + en;
                Cb[(long)m * ldc + n] = (OutT)(acc[i][j][r] + bi);
            }
        }
    }
}

// ---------------- context via MFMA: ctxP[s][bh][e*64+d] --------------------
// Per (bh, slab s): C[m=e][n=d] = sum_l v[e,l] k[d,l] over slab's 256 l's.
// A = v rows (l-fast), B = k rows (l-fast) -> zero repacking.
// Same 2-phase dbuf pipeline as gemm_mfma.
__global__ __launch_bounds__(256)
void context_mfma(const _Float16* __restrict__ kv, float* __restrict__ ctxP)
{
    const int bh = blockIdx.y;             // 0..63
    const int b = bh >> 3, h = bh & 7;
    const int l0 = blockIdx.x * (4096 / CSPLIT);   // 256-wide l slab

    __shared__ _Float16 As0[64 * 32];   // v tile [e][32]
    __shared__ _Float16 As1[64 * 32];
    __shared__ _Float16 Bs0[64 * 32];   // k tile [d][32]
    __shared__ _Float16 Bs1[64 * 32];
    const int tid  = threadIdx.x;
    const int lane = tid & 63;
    const int wave = tid >> 6;
    const int sr = tid >> 2;           // 0..63
    const int sc = (tid & 3) * 8;
    const int wm = (wave & 1) * 32;
    const int wn = (wave >> 1) * 32;
    const int fm = lane & 15;
    const int fk = (lane >> 4) * 8;

    const _Float16* vg = kv + (long)b * 4194304 + (long)(512 + h * 64 + sr) * 4096 + l0 + sc;
    const _Float16* kg = kv + (long)b * 4194304 + (long)(h * 64 + sr) * 4096 + l0 + sc;

    floatx4 acc[2][2];
#pragma unroll
    for (int i = 0; i < 2; ++i)
#pragma unroll
        for (int j = 0; j < 2; ++j) acc[i][j] = (floatx4)0.0f;

#define STAGE_C(AS, BS, K0) do { \
    async_lds16(vg + (K0), &AS[tid * 8]); \
    async_lds16(kg + (K0), &BS[tid * 8]); \
} while (0)

#define COMPUTE_C(AS, BS) do { \
    half8_t a_[2], b_[2]; \
    _Pragma("unroll") \
    for (int i = 0; i < 2; ++i) \
        a_[i] = *(const half8_t*)&AS[(wm + i * 16 + fm) * 32 + fk]; \
    _Pragma("unroll") \
    for (int j = 0; j < 2; ++j) \
        b_[j] = *(const half8_t*)&BS[(wn + j * 16 + fm) * 32 + fk]; \
    __builtin_amdgcn_s_setprio(1); \
    _Pragma("unroll") \
    for (int i = 0; i < 2; ++i) \
    _Pragma("unroll") \
        for (int j = 0; j < 2; ++j) \
            acc[i][j] = __builtin_amdgcn_mfma_f32_16x16x32_f16( \
                a_[i], b_[j], acc[i][j], 0, 0, 0); \
    __builtin_amdgcn_s_setprio(0); \
} while (0)

    STAGE_C(As0, Bs0, 0);
    WAIT_VM0_BARRIER();

    int k0 = 0;
    const int KTOT = 4096 / CSPLIT;
    while (true) {
        if (k0 + 32 < KTOT) STAGE_C(As1, Bs1, k0 + 32);
        COMPUTE_C(As0, Bs0);
        WAIT_VM0_BARRIER();
        k0 += 32;
        if (k0 >= KTOT) break;
        if (k0 + 32 < KTOT) STAGE_C(As0, Bs0, k0 + 32);
        COMPUTE_C(As1, Bs1);
        WAIT_VM0_BARRIER();
        k0 += 32;
        if (k0 >= KTOT) break;
    }
#undef STAGE_C
#undef COMPUTE_C

    const int em = (lane >> 4) * 4;
    const int en = lane & 15;
    float* base = ctxP + ((long)blockIdx.x * 64 + bh) * 4096;
#pragma unroll
    for (int i = 0; i < 2; ++i)
#pragma unroll
        for (int r = 0; r < 4; ++r)
#pragma unroll
            for (int j = 0; j < 2; ++j)
                base[(wm + i * 16 + em + r) * 64 + wn + j * 16 + en] = acc[i][j][r];
}

// ---------------- transpose + fp32->fp16 convert ---------------------------
// src: [R][Cc] fp32 (ld_s). dst: [Cc][R] f16 (ld_d). grid (Cc/64, R/64, batch).
__global__ __launch_bounds__(256)
void transpose_cvt(const float* __restrict__ src, int ld_s, long sB,
                   _Float16* __restrict__ dst, int ld_d, long dB)
{
    __shared__ float tile[64][65];
    const int c0 = blockIdx.x * 64;
    const int r0 = blockIdx.y * 64;
    const float* S = src + (long)blockIdx.z * sB;
    _Float16* D = dst + (long)blockIdx.z * dB;
    const int t = threadIdx.x;
    const int lr = t >> 4;
    const int lc = (t & 15) * 4;
#pragma unroll
    for (int i = 0; i < 4; ++i) {
        const float4 v = *(const float4*)(S + (long)(r0 + lr + 16 * i) * ld_s + c0 + lc);
        tile[lr + 16 * i][lc + 0] = v.x;
        tile[lr + 16 * i][lc + 1] = v.y;
        tile[lr + 16 * i][lc + 2] = v.z;
        tile[lr + 16 * i][lc + 3] = v.w;
    }
    __syncthreads();
    const int rl = (t & 15) * 4;   // dst col base (src row)
    const int cl = t >> 4;         // dst row (src col)
#pragma unroll
    for (int i = 0; i < 4; ++i) {
        const int c = cl + 16 * i;
        half4_t o;
        o[0] = (_Float16)tile[rl + 0][c];
        o[1] = (_Float16)tile[rl + 1][c];
        o[2] = (_Float16)tile[rl + 2][c];
        o[3] = (_Float16)tile[rl + 3][c];
        *(half4_t*)(D + (long)(c0 + c) * ld_d + r0 + rl) = o;
    }
}

// ---------------- wqs[c'][g] = SCALE * w_qkv[c'][g], f16 -------------------
__global__ __launch_bounds__(256)
void scale_wq_kernel(const float* __restrict__ w_qkv, _Float16* __restrict__ wqs)
{
    const int c = blockIdx.x;
    const int t = threadIdx.x;
    const float2 v = *(const float2*)(w_qkv + (long)c * 1536 + t * 2);
    half2_t o;
    o[0] = (_Float16)(v.x * SCALE_);
    o[1] = (_Float16)(v.y * SCALE_);
    *(half2_t*)(wqs + (long)c * 512 + t * 2) = o;
}

// ---------------- softmax over L per (b, f<512) row, f16 in place ----------
__global__ __launch_bounds__(256)
void softmax_rows_h(_Float16* __restrict__ kv)
{
    const int row = blockIdx.x;            // 0..4095
    const int b = row >> 9, f = row & 511;
    _Float16* p = kv + (long)b * 4194304 + (long)f * 4096;
    const int tid = threadIdx.x;

    half8_t h0 = *(const half8_t*)(p + tid * 16);
    half8_t h1 = *(const half8_t*)(p + tid * 16 + 8);
    float v[16];
#pragma unroll
    for (int i = 0; i < 8; ++i) { v[i] = (float)h0[i]; v[8 + i] = (float)h1[i]; }

    float mx = -3.4e38f;
#pragma unroll
    for (int i = 0; i < 16; ++i) mx = fmaxf(mx, v[i]);
#pragma unroll
    for (int off = 32; off > 0; off >>= 1)
        mx = fmaxf(mx, __shfl_down(mx, off));

    __shared__ float red[8];
    if ((tid & 63) == 0) red[tid >> 6] = mx;
    __syncthreads();
    mx = fmaxf(fmaxf(red[0], red[1]), fmaxf(red[2], red[3]));

    float s = 0.0f;
#pragma unroll
    for (int i = 0; i < 16; ++i) { v[i] = __expf(v[i] - mx); s += v[i]; }
#pragma unroll
    for (int off = 32; off > 0; off >>= 1)
        s += __shfl_down(s, off);
    if ((tid & 63) == 0) red[4 + (tid >> 6)] = s;
    __syncthreads();
    const float inv = 1.0f / (red[4] + red[5] + red[6] + red[7]);

#pragma unroll
    for (int i = 0; i < 8; ++i) {
        h0[i] = (_Float16)(v[i] * inv);
        h1[i] = (_Float16)(v[8 + i] * inv);
    }
    *(half8_t*)(p + tid * 16) = h0;
    *(half8_t*)(p + tid * 16 + 8) = h1;
}

// ---- a2tT[b][c][g] = (sum_e (sum_s ctxP)[e][d] w_out[(h,e),c])^T, f16 -----
// output layout [b][c][g], g fast (k-fast A/B operand for the M-build MFMA)
__global__ __launch_bounds__(256)
void a2t_kernel(const float* __restrict__ ctxP, const float* __restrict__ w_out,
                _Float16* __restrict__ a2tT)
{
    const int ct = blockIdx.x, h = blockIdx.y, b = blockIdx.z;
    __shared__ float cs[64][64];      // cs[e][d]
    __shared__ float wsh[64][128];    // wsh[e][c]
    __shared__ _Float16 so[128][64];  // so[c_local][d]
    const int tid = threadIdx.x;
    {
        const int lr = tid >> 4, lc4 = (tid & 15) * 4;
        floatx4 accv[4];
#pragma unroll
        for (int i = 0; i < 4; ++i) accv[i] = (floatx4)0.0f;
        for (int s = 0; s < CSPLIT; ++s) {
            const float* cbase = ctxP + ((long)s * 64 + b * 8 + h) * 4096;
#pragma unroll
            for (int i = 0; i < 4; ++i)
                accv[i] += *(const floatx4*)(cbase + (lr + 16 * i) * 64 + lc4);
        }
#pragma unroll
        for (int i = 0; i < 4; ++i)
            *(floatx4*)&cs[lr + 16 * i][lc4] = accv[i];

        const float* wbase = w_out + (long)(h * 64) * 512 + ct * 128;
        const int wr = tid >> 5, wc4 = (tid & 31) * 4;
#pragma unroll
        for (int i = 0; i < 8; ++i) {
            const int e = wr + 8 * i;
            *(float4*)&wsh[e][wc4] = *(const float4*)(wbase + (long)e * 512 + wc4);
        }
    }
    __syncthreads();
    const int tx = tid & 15, ty = tid >> 4;   // c: tx*8+j, d: ty*4+i
    float acc[4][8] = {};
    for (int e = 0; e < 64; ++e) {
        float a[4], bv[8];
#pragma unroll
        for (int i = 0; i < 4; ++i) a[i] = cs[e][ty * 4 + i];
#pragma unroll
        for (int j = 0; j < 8; ++j) bv[j] = wsh[e][tx * 8 + j];
#pragma unroll
        for (int i = 0; i < 4; ++i)
#pragma unroll
            for (int j = 0; j < 8; ++j)
                acc[i][j] = fmaf(a[i], bv[j], acc[i][j]);
    }
#pragma unroll
    for (int i = 0; i < 4; ++i)
#pragma unroll
        for (int j = 0; j < 8; ++j)
            so[tx * 8 + j][ty * 4 + i] = (_Float16)acc[i][j];
    __syncthreads();
    // coalesced f16 write-out: 1024 chunks of 8 halfs
#pragma unroll
    for (int q = tid; q < 1024; q += 256) {
        const int c_local = q >> 3, co = (q & 7) * 8;
        *(half8_t*)(a2tT + (long)b * 262144 + (long)(ct * 128 + c_local) * 512
                    + h * 64 + co) = *(const half8_t*)&so[c_local][co];
    }
}

extern "C" void kernel_launch(void* const* d_in, const int* in_sizes, int n_in,
                              void* d_out, int out_size, void* d_ws, size_t ws_size,
                              hipStream_t stream)
{
    const float* x      = (const float*)d_in[0];   // (8,512,4096)
    const float* w_qkv  = (const float*)d_in[1];   // (512,1536)
    const float* w_out  = (const float*)d_in[2];   // (512,512)
    const float* b_out  = (const float*)d_in[3];   // (512,)
    float* out = (float*)d_out;                    // (8,512,4096)

    char* wsb = (char*)d_ws;                       // ~122 MB total
    _Float16* kv   = (_Float16*)(wsb);             // 64 MB  [b][f][l]
    _Float16* xT   = (_Float16*)(wsb + 67108864);  // 32 MB  [b][l][c]
    _Float16* wkvT = (_Float16*)(wsb + 100663296); // 1 MB   [f][c]
    _Float16* wqs  = (_Float16*)(wsb + 101711872); // 0.5 MB [c'][g]
    _Float16* a2tT = (_Float16*)(wsb + 102236160); // 4 MB   [b][c][g]
    _Float16* mf   = (_Float16*)(wsb + 106430464); // 4 MB   [b][c][c']
    float*    ctxP = (float*)   (wsb + 110624768); // 16 MB  [s][bh][e*64+d]

    // xT = transpose+cvt(x): src rows c=512, cols l=4096
    transpose_cvt<<<dim3(64, 8, 8), 256, 0, stream>>>(
        x, 4096, 2097152L, xT, 512, 2097152L);
    // wkvT[f][c]: src rows c=512 (ld 1536, offset 512), cols f=1024
    transpose_cvt<<<dim3(16, 8, 1), 256, 0, stream>>>(
        w_qkv + 512, 1536, 0L, wkvT, 512, 0L);
    // wqs[c'][g] = SCALE * w_qkv[c'][g]
    scale_wq_kernel<<<dim3(512), 256, 0, stream>>>(w_qkv, wqs);

    // K1: kv[b][f][l] = sum_c wkvT[f][c] * xT[b][l][c]
    gemm_mfma<_Float16><<<dim3(32, 8, 8), 256, 0, stream>>>(
        wkvT, 0L, 512, xT, 2097152L, kv, 4096, 4194304L, nullptr);

    // K2: softmax over L on the k half
    softmax_rows_h<<<dim3(4096), 256, 0, stream>>>(kv);

    // K3: context partials via MFMA (no atomics, no memset)
    context_mfma<<<dim3(CSPLIT, 64), 256, 0, stream>>>(kv, ctxP);

    // K4a: a2tT (reduces the CSPLIT partials on load)
    a2t_kernel<<<dim3(4, 8, 8), 256, 0, stream>>>(ctxP, w_out, a2tT);

    // K4m: mf[b][c][c'] = sum_g a2tT[b][c][g] * wqs[c'][g]   (= M^T, f16)
    gemm_mfma<_Float16><<<dim3(4, 4, 8), 256, 0, stream>>>(
        a2tT, 262144L, 512, wqs, 0L, mf, 512, 262144L, nullptr);

    // K5: out[b][c][l] = sum_c' mf[b][c][c'] * xT[b][l][c'] + b_out[c]
    gemm_mfma<float><<<dim3(32, 4, 8), 256, 0, stream>>>(
        mf, 262144L, 512, xT, 2097152L, out, 4096, 2097152L, b_out);
}

// Round 2
// 264.977 us; speedup vs baseline: 1.0789x; 1.0789x over previous
//
#include <hip/hip_runtime.h>

// LinearAttention, fp16-MFMA restructuring (round 5).
//   xT   = transpose+cvt(x)          [b][l][c] f16   (B-operand for K1,K5)
//   kv   = wkvT @ xT^T  (MFMA)       [b][f][l] f16, f<512:k, f>=512:v
//   k    = softmax_L(k)              in place, f16
//   ctxP = v k^T partials (MFMA, K split 16)  [s][bh][e*64+d] f32
//   a2tT = (sum_s ctxP . w_out)^T    [b][c][g] f16  (k-fast for M-build)
//   Mf   = a2tT @ wqs^T (MFMA)       [b][c][c'] f16 = A-operand of K5
//   out  = Mf @ xT^T + b_out (MFMA, fp32 out)
// Round-5: round-4's 2-phase dbuf REVERTED (regressed, m99/m100 reproduced).
// K1/K5 moved to gemm256: 256x256 tile, BK=64, 8 waves (2Mx4N), 8-phase
// schedule with counted vmcnt(4), raw s_barrier, T2 XOR-swizzled LDS
// (inverse-swizzled global source + linear global_load_lds dest), T5 setprio.
// Wave quadrants are strided (qm*128 + wm2*64) so phase (qm,qn) touches only
// LDS half-tiles A[qm],B[qn]; staging order A0,B0,B1,A1 gives every half-tile
// >=1 full phase of in-flight latency before first consumption under vmcnt(4).

typedef _Float16 half2_t __attribute__((ext_vector_type(2)));
typedef _Float16 half4_t __attribute__((ext_vector_type(4)));
typedef _Float16 half8_t __attribute__((ext_vector_type(8)));
typedef float    floatx4 __attribute__((ext_vector_type(4)));

#define SCALE_ 0.125f
#define CSPLIT 16

__device__ __forceinline__ void async_lds16(const _Float16* g, _Float16* l) {
    __builtin_amdgcn_global_load_lds(
        (const __attribute__((address_space(1))) void*)g,
        (__attribute__((address_space(3))) void*)l,
        16, 0, 0);
}

#define FENCE() asm volatile("" ::: "memory")
#define BAR()  do { FENCE(); __builtin_amdgcn_s_barrier(); FENCE(); } while (0)
#define VMW4() asm volatile("s_waitcnt vmcnt(4)" ::: "memory")
#define VMW0() asm volatile("s_waitcnt vmcnt(0)" ::: "memory")

// ---------------- 256x256 8-phase MFMA GEMM ---------------------------------
// C[m][n] = sum_k A[m][k]*B[n][k] (+bias[m]).  A:[M][K] k-fast, B:[N][K]
// k-fast, C:[M][N].  Requires M%256==0, N%256==0, K%64==0.
template <typename OutT>
__global__ __launch_bounds__(512, 2)
void gemm256(const _Float16* __restrict__ A, long aBatch, int K,
             const _Float16* __restrict__ B, long bBatch,
             OutT* __restrict__ C, int ldc, long cBatch,
             const float* __restrict__ bias)
{
    // 128 KB: [dbuf(2)][A=0/B=1][half(2)][128*64 f16 = 16KB]
    __shared__ _Float16 smem[65536];
    const int tid  = threadIdx.x;
    const int lane = tid & 63;
    const int wave = tid >> 6;
    const int wm2 = wave >> 2;          // 0..1 (M split)
    const int wn4 = wave & 3;           // 0..3 (N split)
    const int m0 = blockIdx.y * 256;
    const int n0 = blockIdx.x * 256;
    const long bz = blockIdx.z;

    // ---- staging map: thread -> (row = tid>>3 (+64*j), phys granule tid&7)
    // inverse-swizzled SOURCE: physical granule g at row r holds logical
    // granule g^(r&7)  (rule #21: linear LDS dest, pre-swizzled global src)
    const int srow = tid >> 3;
    const int sxor = (((tid & 7) ^ (srow & 7)) << 3);   // elems
    const _Float16* pA = A + bz * aBatch + (long)(m0 + srow) * K + sxor;
    const _Float16* pB = B + bz * bBatch + (long)(n0 + srow) * K + sxor;
    _Float16* ldst = &smem[tid * 8];

    // stage one half-tile (128 rows x 64 cols) of K-tile t_: 2 x gload_lds16
#define STG(t_, ab_, h_, pG_) do { \
    async_lds16((pG_) + (long)((h_) * 128) * K + (t_) * 64, \
                ldst + ((t_) & 1) * 32768 + (ab_) * 16384 + (h_) * 8192); \
    async_lds16((pG_) + (long)((h_) * 128 + 64) * K + (t_) * 64, \
                ldst + ((t_) & 1) * 32768 + (ab_) * 16384 + (h_) * 8192 + 4096); \
} while (0)

    // ---- fragment read offsets (swizzled ds_read side)
    const int fm  = lane & 15;
    const int fkg = lane >> 4;          // 0..3
    int aRow[4], bRow[2], gxo[2];
#pragma unroll
    for (int i = 0; i < 4; ++i) aRow[i] = (wm2 * 64 + i * 16 + fm) << 6;
#pragma unroll
    for (int j = 0; j < 2; ++j) bRow[j] = (wn4 * 32 + j * 16 + fm) << 6;
#pragma unroll
    for (int k = 0; k < 2; ++k) gxo[k] = (((k * 4 + fkg) ^ (fm & 7)) << 3);

    floatx4 acc[8][4];
#pragma unroll
    for (int i = 0; i < 8; ++i)
#pragma unroll
        for (int j = 0; j < 4; ++j) acc[i][j] = (floatx4)0.0f;

    half8_t aF[8], bF0[4], bF1[4];

#define LDA_(d_, qm_) do { \
    const _Float16* base_ = &smem[(d_) * 32768 + (qm_) * 8192]; \
    _Pragma("unroll") \
    for (int i = 0; i < 4; ++i) \
    _Pragma("unroll") \
        for (int k = 0; k < 2; ++k) \
            aF[i * 2 + k] = *(const half8_t*)&base_[aRow[i] + gxo[k]]; \
} while (0)

#define LDB_(d_, qn_, BF) do { \
    const _Float16* base_ = &smem[(d_) * 32768 + 16384 + (qn_) * 8192]; \
    _Pragma("unroll") \
    for (int j = 0; j < 2; ++j) \
    _Pragma("unroll") \
        for (int k = 0; k < 2; ++k) \
            BF[j * 2 + k] = *(const half8_t*)&base_[bRow[j] + gxo[k]]; \
} while (0)

#define MFMA16(qm_, qn_, BF) do { \
    __builtin_amdgcn_s_setprio(1); \
    _Pragma("unroll") \
    for (int i = 0; i < 4; ++i) \
    _Pragma("unroll") \
        for (int j = 0; j < 2; ++j) \
    _Pragma("unroll") \
            for (int k = 0; k < 2; ++k) \
                acc[(qm_) * 4 + i][(qn_) * 2 + j] = \
                    __builtin_amdgcn_mfma_f32_16x16x32_f16( \
                        aF[i * 2 + k], BF[j * 2 + k], \
                        acc[(qm_) * 4 + i][(qn_) * 2 + j], 0, 0, 0); \
    __builtin_amdgcn_s_setprio(0); \
} while (0)

    // prologue: tile 0 -> buf 0 (8 loads), drain once
    STG(0, 0, 0, pA); STG(0, 0, 1, pA);
    STG(0, 1, 0, pB); STG(0, 1, 1, pB);
    VMW0(); BAR();

    const int T = K >> 6;
    for (int t = 0; t < T; ++t) {
        const int d = t & 1;
        const bool pf = (t + 1 < T);
        // phase 0: quadrant (0,0); stage A-half0 of t+1
        LDA_(d, 0); LDB_(d, 0, bF0);
        if (pf) STG(t + 1, 0, 0, pA);
        BAR();
        MFMA16(0, 0, bF0);
        VMW4(); BAR();
        // phase 1: quadrant (0,1); stage B-half0 of t+1
        LDB_(d, 1, bF1);
        if (pf) STG(t + 1, 1, 0, pB);
        BAR();
        MFMA16(0, 1, bF1);
        VMW4(); BAR();
        // phase 2: quadrant (1,1); stage B-half1 of t+1
        LDA_(d, 1);
        if (pf) STG(t + 1, 1, 1, pB);
        BAR();
        MFMA16(1, 1, bF1);
        VMW4(); BAR();
        // phase 3: quadrant (1,0); stage A-half1 of t+1
        if (pf) STG(t + 1, 0, 1, pA);
        BAR();
        MFMA16(1, 0, bF0);
        VMW4(); BAR();
    }
#undef STG
#undef LDA_
#undef LDB_
#undef MFMA16

    // C/D layout: n = lane&15, m = (lane>>4)*4 + reg   [m89/m91-verified]
    const int em = (lane >> 4) * 4;
    const int en = lane & 15;
    OutT* Cb = C + bz * cBatch;
#pragma unroll
    for (int qm = 0; qm < 2; ++qm)
#pragma unroll
        for (int i = 0; i < 4; ++i)
#pragma unroll
            for (int r = 0; r < 4; ++r) {
                const int m = m0 + qm * 128 + wm2 * 64 + i * 16 + em + r;
                const float bi = bias ? bias[m] : 0.0f;
#pragma unroll
                for (int qn = 0; qn < 2; ++qn)
#pragma unroll
                    for (int j = 0; j < 2; ++j) {
                        const int n = n0 + qn * 128 + wn4 * 32 + j * 16 + en;
                        Cb[(long)m * ldc + n] =
                            (OutT)(acc[qm * 4 + i][qn * 2 + j][r] + bi);
                    }
            }
}

// ---------------- MFMA GEMM (128x128, round-3 proven form) ------------------
// Used only for K4m (small). A:[M][K] k-fast, B:[N][K] k-fast, C:[M][N].
template <typename OutT>
__global__ __launch_bounds__(256)
void gemm_mfma(const _Float16* __restrict__ A, long aBatch, int K,
               const _Float16* __restrict__ B, long bBatch,
               OutT* __restrict__ C, int ldc, long cBatch,
               const float* __restrict__ bias)
{
    __shared__ _Float16 As[128 * 32];
    __shared__ _Float16 Bs[128 * 32];
    const int tid  = threadIdx.x;
    const int lane = tid & 63;
    const int wave = tid >> 6;
    const int m0 = blockIdx.y * 128;
    const int n0 = blockIdx.x * 128;
    const long bz = blockIdx.z;
    const _Float16* Ag = A + bz * aBatch + (long)m0 * K;
    const _Float16* Bg = B + bz * bBatch + (long)n0 * K;

    const int sr = tid >> 2;
    const int sc = (tid & 3) * 8;

    const int wm = (wave & 1) * 64;
    const int wn = (wave >> 1) * 64;
    const int fm = lane & 15;
    const int fk = (lane >> 4) * 8;

    floatx4 acc[4][4];
#pragma unroll
    for (int i = 0; i < 4; ++i)
#pragma unroll
        for (int j = 0; j < 4; ++j) acc[i][j] = (floatx4)0.0f;

    for (int k0 = 0; k0 < K; k0 += 32) {
        __syncthreads();
        async_lds16(Ag + (long)sr * K + k0 + sc,        &As[tid * 8]);
        async_lds16(Ag + (long)(sr + 64) * K + k0 + sc, &As[2048 + tid * 8]);
        async_lds16(Bg + (long)sr * K + k0 + sc,        &Bs[tid * 8]);
        async_lds16(Bg + (long)(sr + 64) * K + k0 + sc, &Bs[2048 + tid * 8]);
        __syncthreads();

        half8_t a[4], b[4];
#pragma unroll
        for (int i = 0; i < 4; ++i)
            a[i] = *(const half8_t*)&As[(wm + i * 16 + fm) * 32 + fk];
#pragma unroll
        for (int j = 0; j < 4; ++j)
            b[j] = *(const half8_t*)&Bs[(wn + j * 16 + fm) * 32 + fk];
#pragma unroll
        for (int i = 0; i < 4; ++i)
#pragma unroll
            for (int j = 0; j < 4; ++j)
                acc[i][j] = __builtin_amdgcn_mfma_f32_16x16x32_f16(
                    a[i], b[j], acc[i][j], 0, 0, 0);
    }

    const int em = (lane >> 4) * 4;
    const int en = lane & 15;
    OutT* Cb = C + bz * cBatch;
#pragma unroll
    for (int i = 0; i < 4; ++i) {
#pragma unroll
        for (int r = 0; r < 4; ++r) {
            const int m = m0 + wm + i * 16 + em + r;
            const float bi = bias ? bias[m] : 0.0f;
#pragma unroll
            for (int j = 0; j < 4; ++j) {
                const int n = n0 + wn + j * 16 + en;
                Cb[(long)m * ldc + n] = (OutT)(acc[i][j][r] + bi);
            }
        }
    }
}

// ---------------- context via MFMA: ctxP[s][bh][e*64+d] --------------------
__global__ __launch_bounds__(256)
void context_mfma(const _Float16* __restrict__ kv, float* __restrict__ ctxP)
{
    const int bh = blockIdx.y;             // 0..63
    const int b = bh >> 3, h = bh & 7;
    const int l0 = blockIdx.x * (4096 / CSPLIT);   // 256-wide l slab
    const _Float16* vbase = kv + (long)b * 4194304 + (long)(512 + h * 64) * 4096;
    const _Float16* kbase = kv + (long)b * 4194304 + (long)(h * 64) * 4096;

    __shared__ _Float16 As[64 * 32];   // v tile [e][32]
    __shared__ _Float16 Bs[64 * 32];   // k tile [d][32]
    const int tid  = threadIdx.x;
    const int lane = tid & 63;
    const int wave = tid >> 6;
    const int sr = tid >> 2;
    const int sc = (tid & 3) * 8;
    const int wm = (wave & 1) * 32;
    const int wn = (wave >> 1) * 32;
    const int fm = lane & 15;
    const int fk = (lane >> 4) * 8;

    floatx4 acc[2][2];
#pragma unroll
    for (int i = 0; i < 2; ++i)
#pragma unroll
        for (int j = 0; j < 2; ++j) acc[i][j] = (floatx4)0.0f;

    for (int k0 = 0; k0 < 4096 / CSPLIT; k0 += 32) {
        __syncthreads();
        async_lds16(vbase + (long)sr * 4096 + l0 + k0 + sc, &As[tid * 8]);
        async_lds16(kbase + (long)sr * 4096 + l0 + k0 + sc, &Bs[tid * 8]);
        __syncthreads();

        half8_t a[2], b2[2];
#pragma unroll
        for (int i = 0; i < 2; ++i)
            a[i] = *(const half8_t*)&As[(wm + i * 16 + fm) * 32 + fk];
#pragma unroll
        for (int j = 0; j < 2; ++j)
            b2[j] = *(const half8_t*)&Bs[(wn + j * 16 + fm) * 32 + fk];
#pragma unroll
        for (int i = 0; i < 2; ++i)
#pragma unroll
            for (int j = 0; j < 2; ++j)
                acc[i][j] = __builtin_amdgcn_mfma_f32_16x16x32_f16(
                    a[i], b2[j], acc[i][j], 0, 0, 0);
    }

    const int em = (lane >> 4) * 4;
    const int en = lane & 15;
    float* base = ctxP + ((long)blockIdx.x * 64 + bh) * 4096;
#pragma unroll
    for (int i = 0; i < 2; ++i)
#pragma unroll
        for (int r = 0; r < 4; ++r)
#pragma unroll
            for (int j = 0; j < 2; ++j)
                base[(wm + i * 16 + em + r) * 64 + wn + j * 16 + en] = acc[i][j][r];
}

// ---------------- transpose + fp32->fp16 convert ---------------------------
__global__ __launch_bounds__(256)
void transpose_cvt(const float* __restrict__ src, int ld_s, long sB,
                   _Float16* __restrict__ dst, int ld_d, long dB)
{
    __shared__ float tile[64][65];
    const int c0 = blockIdx.x * 64;
    const int r0 = blockIdx.y * 64;
    const float* S = src + (long)blockIdx.z * sB;
    _Float16* D = dst + (long)blockIdx.z * dB;
    const int t = threadIdx.x;
    const int lr = t >> 4;
    const int lc = (t & 15) * 4;
#pragma unroll
    for (int i = 0; i < 4; ++i) {
        const float4 v = *(const float4*)(S + (long)(r0 + lr + 16 * i) * ld_s + c0 + lc);
        tile[lr + 16 * i][lc + 0] = v.x;
        tile[lr + 16 * i][lc + 1] = v.y;
        tile[lr + 16 * i][lc + 2] = v.z;
        tile[lr + 16 * i][lc + 3] = v.w;
    }
    __syncthreads();
    const int rl = (t & 15) * 4;
    const int cl = t >> 4;
#pragma unroll
    for (int i = 0; i < 4; ++i) {
        const int c = cl + 16 * i;
        half4_t o;
        o[0] = (_Float16)tile[rl + 0][c];
        o[1] = (_Float16)tile[rl + 1][c];
        o[2] = (_Float16)tile[rl + 2][c];
        o[3] = (_Float16)tile[rl + 3][c];
        *(half4_t*)(D + (long)(c0 + c) * ld_d + r0 + rl) = o;
    }
}

// ---------------- wqs[c'][g] = SCALE * w_qkv[c'][g], f16 -------------------
__global__ __launch_bounds__(256)
void scale_wq_kernel(const float* __restrict__ w_qkv, _Float16* __restrict__ wqs)
{
    const int c = blockIdx.x;
    const int t = threadIdx.x;
    const float2 v = *(const float2*)(w_qkv + (long)c * 1536 + t * 2);
    half2_t o;
    o[0] = (_Float16)(v.x * SCALE_);
    o[1] = (_Float16)(v.y * SCALE_);
    *(half2_t*)(wqs + (long)c * 512 + t * 2) = o;
}

// ---------------- softmax over L per (b, f<512) row, f16 in place ----------
__global__ __launch_bounds__(256)
void softmax_rows_h(_Float16* __restrict__ kv)
{
    const int row = blockIdx.x;            // 0..4095
    const int b = row >> 9, f = row & 511;
    _Float16* p = kv + (long)b * 4194304 + (long)f * 4096;
    const int tid = threadIdx.x;

    half8_t h0 = *(const half8_t*)(p + tid * 16);
    half8_t h1 = *(const half8_t*)(p + tid * 16 + 8);
    float v[16];
#pragma unroll
    for (int i = 0; i < 8; ++i) { v[i] = (float)h0[i]; v[8 + i] = (float)h1[i]; }

    float mx = -3.4e38f;
#pragma unroll
    for (int i = 0; i < 16; ++i) mx = fmaxf(mx, v[i]);
#pragma unroll
    for (int off = 32; off > 0; off >>= 1)
        mx = fmaxf(mx, __shfl_down(mx, off));

    __shared__ float red[8];
    if ((tid & 63) == 0) red[tid >> 6] = mx;
    __syncthreads();
    mx = fmaxf(fmaxf(red[0], red[1]), fmaxf(red[2], red[3]));

    float s = 0.0f;
#pragma unroll
    for (int i = 0; i < 16; ++i) { v[i] = __expf(v[i] - mx); s += v[i]; }
#pragma unroll
    for (int off = 32; off > 0; off >>= 1)
        s += __shfl_down(s, off);
    if ((tid & 63) == 0) red[4 + (tid >> 6)] = s;
    __syncthreads();
    const float inv = 1.0f / (red[4] + red[5] + red[6] + red[7]);

#pragma unroll
    for (int i = 0; i < 8; ++i) {
        h0[i] = (_Float16)(v[i] * inv);
        h1[i] = (_Float16)(v[8 + i] * inv);
    }
    *(half8_t*)(p + tid * 16) = h0;
    *(half8_t*)(p + tid * 16 + 8) = h1;
}

// ---- a2tT[b][c][g] = (sum_e (sum_s ctxP)[e][d] w_out[(h,e),c])^T, f16 -----
__global__ __launch_bounds__(256)
void a2t_kernel(const float* __restrict__ ctxP, const float* __restrict__ w_out,
                _Float16* __restrict__ a2tT)
{
    const int ct = blockIdx.x, h = blockIdx.y, b = blockIdx.z;
    __shared__ float cs[64][64];      // cs[e][d]
    __shared__ float wsh[64][128];    // wsh[e][c]
    __shared__ _Float16 so[128][64];  // so[c_local][d]
    const int tid = threadIdx.x;
    {
        const int lr = tid >> 4, lc4 = (tid & 15) * 4;
        floatx4 accv[4];
#pragma unroll
        for (int i = 0; i < 4; ++i) accv[i] = (floatx4)0.0f;
        for (int s = 0; s < CSPLIT; ++s) {
            const float* cbase = ctxP + ((long)s * 64 + b * 8 + h) * 4096;
#pragma unroll
            for (int i = 0; i < 4; ++i)
                accv[i] += *(const floatx4*)(cbase + (lr + 16 * i) * 64 + lc4);
        }
#pragma unroll
        for (int i = 0; i < 4; ++i)
            *(floatx4*)&cs[lr + 16 * i][lc4] = accv[i];

        const float* wbase = w_out + (long)(h * 64) * 512 + ct * 128;
        const int wr = tid >> 5, wc4 = (tid & 31) * 4;
#pragma unroll
        for (int i = 0; i < 8; ++i) {
            const int e = wr + 8 * i;
            *(float4*)&wsh[e][wc4] = *(const float4*)(wbase + (long)e * 512 + wc4);
        }
    }
    __syncthreads();
    const int tx = tid & 15, ty = tid >> 4;
    float acc[4][8] = {};
    for (int e = 0; e < 64; ++e) {
        float a[4], bv[8];
#pragma unroll
        for (int i = 0; i < 4; ++i) a[i] = cs[e][ty * 4 + i];
#pragma unroll
        for (int j = 0; j < 8; ++j) bv[j] = wsh[e][tx * 8 + j];
#pragma unroll
        for (int i = 0; i < 4; ++i)
#pragma unroll
            for (int j = 0; j < 8; ++j)
                acc[i][j] = fmaf(a[i], bv[j], acc[i][j]);
    }
#pragma unroll
    for (int i = 0; i < 4; ++i)
#pragma unroll
        for (int j = 0; j < 8; ++j)
            so[tx * 8 + j][ty * 4 + i] = (_Float16)acc[i][j];
    __syncthreads();
#pragma unroll
    for (int q = tid; q < 1024; q += 256) {
        const int c_local = q >> 3, co = (q & 7) * 8;
        *(half8_t*)(a2tT + (long)b * 262144 + (long)(ct * 128 + c_local) * 512
                    + h * 64 + co) = *(const half8_t*)&so[c_local][co];
    }
}

extern "C" void kernel_launch(void* const* d_in, const int* in_sizes, int n_in,
                              void* d_out, int out_size, void* d_ws, size_t ws_size,
                              hipStream_t stream)
{
    const float* x      = (const float*)d_in[0];   // (8,512,4096)
    const float* w_qkv  = (const float*)d_in[1];   // (512,1536)
    const float* w_out  = (const float*)d_in[2];   // (512,512)
    const float* b_out  = (const float*)d_in[3];   // (512,)
    float* out = (float*)d_out;                    // (8,512,4096)

    char* wsb = (char*)d_ws;                       // ~122 MB total
    _Float16* kv   = (_Float16*)(wsb);             // 64 MB  [b][f][l]
    _Float16* xT   = (_Float16*)(wsb + 67108864);  // 32 MB  [b][l][c]
    _Float16* wkvT = (_Float16*)(wsb + 100663296); // 1 MB   [f][c]
    _Float16* wqs  = (_Float16*)(wsb + 101711872); // 0.5 MB [c'][g]
    _Float16* a2tT = (_Float16*)(wsb + 102236160); // 4 MB   [b][c][g]
    _Float16* mf   = (_Float16*)(wsb + 106430464); // 4 MB   [b][c][c']
    float*    ctxP = (float*)   (wsb + 110624768); // 16 MB  [s][bh][e*64+d]

    // xT = transpose+cvt(x): src rows c=512, cols l=4096
    transpose_cvt<<<dim3(64, 8, 8), 256, 0, stream>>>(
        x, 4096, 2097152L, xT, 512, 2097152L);
    // wkvT[f][c]: src rows c=512 (ld 1536, offset 512), cols f=1024
    transpose_cvt<<<dim3(16, 8, 1), 256, 0, stream>>>(
        w_qkv + 512, 1536, 0L, wkvT, 512, 0L);
    // wqs[c'][g] = SCALE * w_qkv[c'][g]
    scale_wq_kernel<<<dim3(512), 256, 0, stream>>>(w_qkv, wqs);

    // K1: kv[b][f][l] = sum_c wkvT[f][c] * xT[b][l][c]   (M=1024,N=4096,K=512)
    gemm256<_Float16><<<dim3(16, 4, 8), 512, 0, stream>>>(
        wkvT, 0L, 512, xT, 2097152L, kv, 4096, 4194304L, nullptr);

    // K2: softmax over L on the k half
    softmax_rows_h<<<dim3(4096), 256, 0, stream>>>(kv);

    // K3: context partials via MFMA
    context_mfma<<<dim3(CSPLIT, 64), 256, 0, stream>>>(kv, ctxP);

    // K4a: a2tT (reduces the CSPLIT partials on load)
    a2t_kernel<<<dim3(4, 8, 8), 256, 0, stream>>>(ctxP, w_out, a2tT);

    // K4m: mf[b][c][c'] = sum_g a2tT[b][c][g] * wqs[c'][g]   (= M^T, f16)
    gemm_mfma<_Float16><<<dim3(4, 4, 8), 256, 0, stream>>>(
        a2tT, 262144L, 512, wqs, 0L, mf, 512, 262144L, nullptr);

    // K5: out[b][c][l] = sum_c' mf[b][c][c'] * xT[b][l][c'] + b_out[c]
    //     (M=512,N=4096,K=512)
    gemm256<float><<<dim3(16, 2, 8), 512, 0, stream>>>(
        mf, 262144L, 512, xT, 2097152L, out, 4096, 2097152L, b_out);
}

// Round 3
// 261.824 us; speedup vs baseline: 1.0919x; 1.0120x over previous
//
#include <hip/hip_runtime.h>

// LinearAttention, fp16-MFMA restructuring (round 6).
//   xT   = transpose+cvt(x)          [b][l][c] f16   (B-operand for K1,K5)
//   kv   = wkvT @ xT^T  (MFMA)       [b][f][l] f16, f<512:k, f>=512:v
//   k    = softmax_L(k)              in place, f16
//   ctxP = v k^T partials (MFMA, K split 16)  [s][bh][e*64+d] f32
//   a2tT = (sum_s ctxP . w_out)^T    [b][c][g] f16  (k-fast for M-build)
//   Mf   = a2tT @ wqs^T (MFMA)       [b][c][c'] f16 = A-operand of K5
//   out  = Mf @ xT^T + b_out (MFMA, fp32 out)
// Round-6 changes to gemm256 (round-5 got conflicts->0 but MfmaUtil stuck 23%):
//  * barriers 8/tile -> 2/tile (end-p0, end-p3 are the only true sync points;
//    waves drift within the tile -> inter-wave MFMA||ds_read overlap).
//  * stage all 4 half-tiles of t+1 during phases 0-1 of t; two vmcnt(4)
//    checks per tile with >=3-phase prefetch distance (VMW0 endgame).
//  * fragment LDS reads via inline-asm ds_read_b128 + manual lgkmcnt(0) +
//    sched_barrier(0)  (defeats compiler-inserted vmcnt(0)-before-ds_read
//    from the LDS-DMA alias hazard; rule #18 fence).
//  * T1 XCD-aware block swizzle: each XCD owns one batch's panel set.

typedef _Float16 half2_t __attribute__((ext_vector_type(2)));
typedef _Float16 half4_t __attribute__((ext_vector_type(4)));
typedef _Float16 half8_t __attribute__((ext_vector_type(8)));
typedef float    floatx4 __attribute__((ext_vector_type(4)));

#define SCALE_ 0.125f
#define CSPLIT 16

typedef __attribute__((address_space(3))) _Float16 lds_half;

__device__ __forceinline__ void async_lds16(const _Float16* g, _Float16* l) {
    __builtin_amdgcn_global_load_lds(
        (const __attribute__((address_space(1))) void*)g,
        (__attribute__((address_space(3))) void*)l,
        16, 0, 0);
}

__device__ __forceinline__ half8_t lds_read16(const lds_half* p) {
    half8_t r;
    asm volatile("ds_read_b128 %0, %1" : "=v"(r) : "v"(p));
    return r;
}

#define FENCE() asm volatile("" ::: "memory")
#define BAR()  do { FENCE(); __builtin_amdgcn_s_barrier(); FENCE(); } while (0)
#define VMW4() asm volatile("s_waitcnt vmcnt(4)" ::: "memory")
#define VMW0() asm volatile("s_waitcnt vmcnt(0)" ::: "memory")
#define LGKM0_SB() do { \
    asm volatile("s_waitcnt lgkmcnt(0)" ::: "memory"); \
    __builtin_amdgcn_sched_barrier(0); \
} while (0)

// ---------------- 256x256 MFMA GEMM, 4-phase counted-vmcnt pipeline --------
// C[m][n] = sum_k A[m][k]*B[n][k] (+bias[m]).  A:[M][K] k-fast, B:[N][K]
// k-fast, C:[M][N].  Requires M%256==0, N%256==0, K%64==0, grid blocks %8==0.
template <typename OutT>
__global__ __launch_bounds__(512, 2)
void gemm256(const _Float16* __restrict__ A, long aBatch, int K,
             const _Float16* __restrict__ B, long bBatch,
             OutT* __restrict__ C, int ldc, long cBatch,
             const float* __restrict__ bias)
{
    // 128 KB: [dbuf(2)][A=0/B=1][half(2)][128*64 f16 = 16KB]
    __shared__ _Float16 smem[65536];
    const int tid  = threadIdx.x;
    const int lane = tid & 63;
    const int wave = tid >> 6;
    const int wm2 = wave >> 2;          // 0..1 (M split)
    const int wn4 = wave & 3;           // 0..3 (N split)

    // T1: XCD swizzle (bijective: nwg % 8 == 0 for all our launches).
    const int nx = gridDim.x, ny = gridDim.y;
    const int nwg = nx * ny * gridDim.z;
    const int bid = blockIdx.x + nx * (blockIdx.y + ny * blockIdx.z);
    const int per = nwg >> 3;
    const int wg  = (bid & 7) * per + (bid >> 3);
    const int yb = wg % ny;
    const int xb = (wg / ny) % nx;
    const int zb = wg / (ny * nx);

    const int m0 = yb * 256;
    const int n0 = xb * 256;
    const long bz = zb;

    // ---- staging map: thread -> (row = tid>>3 (+64/128), phys granule tid&7)
    // inverse-swizzled SOURCE: physical granule g at row r holds logical
    // granule g^(r&7)  (rule #21: linear LDS dest, pre-swizzled global src)
    const int srow = tid >> 3;
    const int sxor = (((tid & 7) ^ (srow & 7)) << 3);   // elems
    const _Float16* pA = A + bz * aBatch + (long)(m0 + srow) * K + sxor;
    const _Float16* pB = B + bz * bBatch + (long)(n0 + srow) * K + sxor;
    _Float16* ldst = &smem[tid * 8];

    // stage one half-tile (128 rows x 64 cols) of K-tile t_: 2 x gload_lds16
#define STG(t_, ab_, h_, pG_) do { \
    async_lds16((pG_) + (long)((h_) * 128) * K + (t_) * 64, \
                ldst + ((t_) & 1) * 32768 + (ab_) * 16384 + (h_) * 8192); \
    async_lds16((pG_) + (long)((h_) * 128 + 64) * K + (t_) * 64, \
                ldst + ((t_) & 1) * 32768 + (ab_) * 16384 + (h_) * 8192 + 4096); \
} while (0)

    // ---- fragment read offsets (swizzled ds_read side), element units
    const int fm  = lane & 15;
    const int fkg = lane >> 4;          // 0..3
    int aRow[4], bRow[2], gxo[2];
#pragma unroll
    for (int i = 0; i < 4; ++i) aRow[i] = (wm2 * 64 + i * 16 + fm) << 6;
#pragma unroll
    for (int j = 0; j < 2; ++j) bRow[j] = (wn4 * 32 + j * 16 + fm) << 6;
#pragma unroll
    for (int k = 0; k < 2; ++k) gxo[k] = (((k * 4 + fkg) ^ (fm & 7)) << 3);

    const lds_half* sm3 = (const lds_half*)&smem[0];

    floatx4 acc[8][4];
#pragma unroll
    for (int i = 0; i < 8; ++i)
#pragma unroll
        for (int j = 0; j < 4; ++j) acc[i][j] = (floatx4)0.0f;

    half8_t aF[8], bF0[4], bF1[4];

#define LDA_(d_, qm_) do { \
    const lds_half* base_ = sm3 + (d_) * 32768 + (qm_) * 8192; \
    _Pragma("unroll") \
    for (int i = 0; i < 4; ++i) \
    _Pragma("unroll") \
        for (int k = 0; k < 2; ++k) \
            aF[i * 2 + k] = lds_read16(base_ + aRow[i] + gxo[k]); \
} while (0)

#define LDB_(d_, qn_, BF) do { \
    const lds_half* base_ = sm3 + (d_) * 32768 + 16384 + (qn_) * 8192; \
    _Pragma("unroll") \
    for (int j = 0; j < 2; ++j) \
    _Pragma("unroll") \
        for (int k = 0; k < 2; ++k) \
            BF[j * 2 + k] = lds_read16(base_ + bRow[j] + gxo[k]); \
} while (0)

#define MFMA16(qm_, qn_, BF) do { \
    __builtin_amdgcn_s_setprio(1); \
    _Pragma("unroll") \
    for (int i = 0; i < 4; ++i) \
    _Pragma("unroll") \
        for (int j = 0; j < 2; ++j) \
    _Pragma("unroll") \
            for (int k = 0; k < 2; ++k) \
                acc[(qm_) * 4 + i][(qn_) * 2 + j] = \
                    __builtin_amdgcn_mfma_f32_16x16x32_f16( \
                        aF[i * 2 + k], BF[j * 2 + k], \
                        acc[(qm_) * 4 + i][(qn_) * 2 + j], 0, 0, 0); \
    __builtin_amdgcn_s_setprio(0); \
} while (0)

    // prologue: tile 0 -> buf 0 (A0,B0,B1,A1 = 8 loads), drain once
    STG(0, 0, 0, pA); STG(0, 1, 0, pB);
    STG(0, 1, 1, pB); STG(0, 0, 1, pA);
    VMW0(); BAR();

    const int T = K >> 6;
    for (int t = 0; t < T; ++t) {
        const int d = t & 1;
        const bool pf = (t + 1 < T);
        // ---- phase 0: quadrant (0,0).  Stage A0,B0 of t+1.
        if (pf) { STG(t + 1, 0, 0, pA); STG(t + 1, 1, 0, pB); }
        LDA_(d, 0);
        LDB_(d, 0, bF0);
        LGKM0_SB();
        MFMA16(0, 0, bF0);
        // sync point 1: B1(t),A1(t) (staged p1 of t-1) must be landed for
        // phases 1-2.  Outstanding: [B1A1(t) 4][A0B0(t+1) 4] -> vmcnt(4).
        if (pf) VMW4(); else VMW0();
        BAR();
        // ---- phase 1: quadrant (0,1).  Stage B1,A1 of t+1.
        if (pf) { STG(t + 1, 1, 1, pB); STG(t + 1, 0, 1, pA); }
        LDB_(d, 1, bF1);
        LGKM0_SB();
        MFMA16(0, 1, bF1);
        // ---- phase 2: quadrant (1,1).  (no barrier: covered by sync 1)
        LDA_(d, 1);
        LGKM0_SB();
        MFMA16(1, 1, bF1);
        // ---- phase 3: quadrant (1,0).  (all frags already in regs)
        MFMA16(1, 0, bF0);
        // sync point 2: A0,B0 of t+1 must be landed before next tile's p0.
        // Outstanding: [A0B0(t+1) 4][B1A1(t+1) 4] -> vmcnt(4).
        if (pf) { VMW4(); BAR(); }
    }
#undef STG
#undef LDA_
#undef LDB_
#undef MFMA16

    // C/D layout: n = lane&15, m = (lane>>4)*4 + reg   [m89/m91-verified]
    const int em = (lane >> 4) * 4;
    const int en = lane & 15;
    OutT* Cb = C + bz * cBatch;
#pragma unroll
    for (int qm = 0; qm < 2; ++qm)
#pragma unroll
        for (int i = 0; i < 4; ++i)
#pragma unroll
            for (int r = 0; r < 4; ++r) {
                const int m = m0 + qm * 128 + wm2 * 64 + i * 16 + em + r;
                const float bi = bias ? bias[m] : 0.0f;
#pragma unroll
                for (int qn = 0; qn < 2; ++qn)
#pragma unroll
                    for (int j = 0; j < 2; ++j) {
                        const int n = n0 + qn * 128 + wn4 * 32 + j * 16 + en;
                        Cb[(long)m * ldc + n] =
                            (OutT)(acc[qm * 4 + i][qn * 2 + j][r] + bi);
                    }
            }
}

// ---------------- MFMA GEMM (128x128, round-3 proven form) ------------------
// Used only for K4m (small). A:[M][K] k-fast, B:[N][K] k-fast, C:[M][N].
template <typename OutT>
__global__ __launch_bounds__(256)
void gemm_mfma(const _Float16* __restrict__ A, long aBatch, int K,
               const _Float16* __restrict__ B, long bBatch,
               OutT* __restrict__ C, int ldc, long cBatch,
               const float* __restrict__ bias)
{
    __shared__ _Float16 As[128 * 32];
    __shared__ _Float16 Bs[128 * 32];
    const int tid  = threadIdx.x;
    const int lane = tid & 63;
    const int wave = tid >> 6;
    const int m0 = blockIdx.y * 128;
    const int n0 = blockIdx.x * 128;
    const long bz = blockIdx.z;
    const _Float16* Ag = A + bz * aBatch + (long)m0 * K;
    const _Float16* Bg = B + bz * bBatch + (long)n0 * K;

    const int sr = tid >> 2;
    const int sc = (tid & 3) * 8;

    const int wm = (wave & 1) * 64;
    const int wn = (wave >> 1) * 64;
    const int fm = lane & 15;
    const int fk = (lane >> 4) * 8;

    floatx4 acc[4][4];
#pragma unroll
    for (int i = 0; i < 4; ++i)
#pragma unroll
        for (int j = 0; j < 4; ++j) acc[i][j] = (floatx4)0.0f;

    for (int k0 = 0; k0 < K; k0 += 32) {
        __syncthreads();
        async_lds16(Ag + (long)sr * K + k0 + sc,        &As[tid * 8]);
        async_lds16(Ag + (long)(sr + 64) * K + k0 + sc, &As[2048 + tid * 8]);
        async_lds16(Bg + (long)sr * K + k0 + sc,        &Bs[tid * 8]);
        async_lds16(Bg + (long)(sr + 64) * K + k0 + sc, &Bs[2048 + tid * 8]);
        __syncthreads();

        half8_t a[4], b[4];
#pragma unroll
        for (int i = 0; i < 4; ++i)
            a[i] = *(const half8_t*)&As[(wm + i * 16 + fm) * 32 + fk];
#pragma unroll
        for (int j = 0; j < 4; ++j)
            b[j] = *(const half8_t*)&Bs[(wn + j * 16 + fm) * 32 + fk];
#pragma unroll
        for (int i = 0; i < 4; ++i)
#pragma unroll
            for (int j = 0; j < 4; ++j)
                acc[i][j] = __builtin_amdgcn_mfma_f32_16x16x32_f16(
                    a[i], b[j], acc[i][j], 0, 0, 0);
    }

    const int em = (lane >> 4) * 4;
    const int en = lane & 15;
    OutT* Cb = C + bz * cBatch;
#pragma unroll
    for (int i = 0; i < 4; ++i) {
#pragma unroll
        for (int r = 0; r < 4; ++r) {
            const int m = m0 + wm + i * 16 + em + r;
            const float bi = bias ? bias[m] : 0.0f;
#pragma unroll
            for (int j = 0; j < 4; ++j) {
                const int n = n0 + wn + j * 16 + en;
                Cb[(long)m * ldc + n] = (OutT)(acc[i][j][r] + bi);
            }
        }
    }
}

// ---------------- context via MFMA: ctxP[s][bh][e*64+d] --------------------
__global__ __launch_bounds__(256)
void context_mfma(const _Float16* __restrict__ kv, float* __restrict__ ctxP)
{
    const int bh = blockIdx.y;             // 0..63
    const int b = bh >> 3, h = bh & 7;
    const int l0 = blockIdx.x * (4096 / CSPLIT);   // 256-wide l slab
    const _Float16* vbase = kv + (long)b * 4194304 + (long)(512 + h * 64) * 4096;
    const _Float16* kbase = kv + (long)b * 4194304 + (long)(h * 64) * 4096;

    __shared__ _Float16 As[64 * 32];   // v tile [e][32]
    __shared__ _Float16 Bs[64 * 32];   // k tile [d][32]
    const int tid  = threadIdx.x;
    const int lane = tid & 63;
    const int wave = tid >> 6;
    const int sr = tid >> 2;
    const int sc = (tid & 3) * 8;
    const int wm = (wave & 1) * 32;
    const int wn = (wave >> 1) * 32;
    const int fm = lane & 15;
    const int fk = (lane >> 4) * 8;

    floatx4 acc[2][2];
#pragma unroll
    for (int i = 0; i < 2; ++i)
#pragma unroll
        for (int j = 0; j < 2; ++j) acc[i][j] = (floatx4)0.0f;

    for (int k0 = 0; k0 < 4096 / CSPLIT; k0 += 32) {
        __syncthreads();
        async_lds16(vbase + (long)sr * 4096 + l0 + k0 + sc, &As[tid * 8]);
        async_lds16(kbase + (long)sr * 4096 + l0 + k0 + sc, &Bs[tid * 8]);
        __syncthreads();

        half8_t a[2], b2[2];
#pragma unroll
        for (int i = 0; i < 2; ++i)
            a[i] = *(const half8_t*)&As[(wm + i * 16 + fm) * 32 + fk];
#pragma unroll
        for (int j = 0; j < 2; ++j)
            b2[j] = *(const half8_t*)&Bs[(wn + j * 16 + fm) * 32 + fk];
#pragma unroll
        for (int i = 0; i < 2; ++i)
#pragma unroll
            for (int j = 0; j < 2; ++j)
                acc[i][j] = __builtin_amdgcn_mfma_f32_16x16x32_f16(
                    a[i], b2[j], acc[i][j], 0, 0, 0);
    }

    const int em = (lane >> 4) * 4;
    const int en = lane & 15;
    float* base = ctxP + ((long)blockIdx.x * 64 + bh) * 4096;
#pragma unroll
    for (int i = 0; i < 2; ++i)
#pragma unroll
        for (int r = 0; r < 4; ++r)
#pragma unroll
            for (int j = 0; j < 2; ++j)
                base[(wm + i * 16 + em + r) * 64 + wn + j * 16 + en] = acc[i][j][r];
}

// ---------------- transpose + fp32->fp16 convert ---------------------------
__global__ __launch_bounds__(256)
void transpose_cvt(const float* __restrict__ src, int ld_s, long sB,
                   _Float16* __restrict__ dst, int ld_d, long dB)
{
    __shared__ float tile[64][65];
    const int c0 = blockIdx.x * 64;
    const int r0 = blockIdx.y * 64;
    const float* S = src + (long)blockIdx.z * sB;
    _Float16* D = dst + (long)blockIdx.z * dB;
    const int t = threadIdx.x;
    const int lr = t >> 4;
    const int lc = (t & 15) * 4;
#pragma unroll
    for (int i = 0; i < 4; ++i) {
        const float4 v = *(const float4*)(S + (long)(r0 + lr + 16 * i) * ld_s + c0 + lc);
        tile[lr + 16 * i][lc + 0] = v.x;
        tile[lr + 16 * i][lc + 1] = v.y;
        tile[lr + 16 * i][lc + 2] = v.z;
        tile[lr + 16 * i][lc + 3] = v.w;
    }
    __syncthreads();
    const int rl = (t & 15) * 4;
    const int cl = t >> 4;
#pragma unroll
    for (int i = 0; i < 4; ++i) {
        const int c = cl + 16 * i;
        half4_t o;
        o[0] = (_Float16)tile[rl + 0][c];
        o[1] = (_Float16)tile[rl + 1][c];
        o[2] = (_Float16)tile[rl + 2][c];
        o[3] = (_Float16)tile[rl + 3][c];
        *(half4_t*)(D + (long)(c0 + c) * ld_d + r0 + rl) = o;
    }
}

// ---------------- wqs[c'][g] = SCALE * w_qkv[c'][g], f16 -------------------
__global__ __launch_bounds__(256)
void scale_wq_kernel(const float* __restrict__ w_qkv, _Float16* __restrict__ wqs)
{
    const int c = blockIdx.x;
    const int t = threadIdx.x;
    const float2 v = *(const float2*)(w_qkv + (long)c * 1536 + t * 2);
    half2_t o;
    o[0] = (_Float16)(v.x * SCALE_);
    o[1] = (_Float16)(v.y * SCALE_);
    *(half2_t*)(wqs + (long)c * 512 + t * 2) = o;
}

// ---------------- softmax over L per (b, f<512) row, f16 in place ----------
__global__ __launch_bounds__(256)
void softmax_rows_h(_Float16* __restrict__ kv)
{
    const int row = blockIdx.x;            // 0..4095
    const int b = row >> 9, f = row & 511;
    _Float16* p = kv + (long)b * 4194304 + (long)f * 4096;
    const int tid = threadIdx.x;

    half8_t h0 = *(const half8_t*)(p + tid * 16);
    half8_t h1 = *(const half8_t*)(p + tid * 16 + 8);
    float v[16];
#pragma unroll
    for (int i = 0; i < 8; ++i) { v[i] = (float)h0[i]; v[8 + i] = (float)h1[i]; }

    float mx = -3.4e38f;
#pragma unroll
    for (int i = 0; i < 16; ++i) mx = fmaxf(mx, v[i]);
#pragma unroll
    for (int off = 32; off > 0; off >>= 1)
        mx = fmaxf(mx, __shfl_down(mx, off));

    __shared__ float red[8];
    if ((tid & 63) == 0) red[tid >> 6] = mx;
    __syncthreads();
    mx = fmaxf(fmaxf(red[0], red[1]), fmaxf(red[2], red[3]));

    float s = 0.0f;
#pragma unroll
    for (int i = 0; i < 16; ++i) { v[i] = __expf(v[i] - mx); s += v[i]; }
#pragma unroll
    for (int off = 32; off > 0; off >>= 1)
        s += __shfl_down(s, off);
    if ((tid & 63) == 0) red[4 + (tid >> 6)] = s;
    __syncthreads();
    const float inv = 1.0f / (red[4] + red[5] + red[6] + red[7]);

#pragma unroll
    for (int i = 0; i < 8; ++i) {
        h0[i] = (_Float16)(v[i] * inv);
        h1[i] = (_Float16)(v[8 + i] * inv);
    }
    *(half8_t*)(p + tid * 16) = h0;
    *(half8_t*)(p + tid * 16 + 8) = h1;
}

// ---- a2tT[b][c][g] = (sum_e (sum_s ctxP)[e][d] w_out[(h,e),c])^T, f16 -----
__global__ __launch_bounds__(256)
void a2t_kernel(const float* __restrict__ ctxP, const float* __restrict__ w_out,
                _Float16* __restrict__ a2tT)
{
    const int ct = blockIdx.x, h = blockIdx.y, b = blockIdx.z;
    __shared__ float cs[64][64];      // cs[e][d]
    __shared__ float wsh[64][128];    // wsh[e][c]
    __shared__ _Float16 so[128][64];  // so[c_local][d]
    const int tid = threadIdx.x;
    {
        const int lr = tid >> 4, lc4 = (tid & 15) * 4;
        floatx4 accv[4];
#pragma unroll
        for (int i = 0; i < 4; ++i) accv[i] = (floatx4)0.0f;
        for (int s = 0; s < CSPLIT; ++s) {
            const float* cbase = ctxP + ((long)s * 64 + b * 8 + h) * 4096;
#pragma unroll
            for (int i = 0; i < 4; ++i)
                accv[i] += *(const floatx4*)(cbase + (lr + 16 * i) * 64 + lc4);
        }
#pragma unroll
        for (int i = 0; i < 4; ++i)
            *(floatx4*)&cs[lr + 16 * i][lc4] = accv[i];

        const float* wbase = w_out + (long)(h * 64) * 512 + ct * 128;
        const int wr = tid >> 5, wc4 = (tid & 31) * 4;
#pragma unroll
        for (int i = 0; i < 8; ++i) {
            const int e = wr + 8 * i;
            *(float4*)&wsh[e][wc4] = *(const float4*)(wbase + (long)e * 512 + wc4);
        }
    }
    __syncthreads();
    const int tx = tid & 15, ty = tid >> 4;
    float acc[4][8] = {};
    for (int e = 0; e < 64; ++e) {
        float a[4], bv[8];
#pragma unroll
        for (int i = 0; i < 4; ++i) a[i] = cs[e][ty * 4 + i];
#pragma unroll
        for (int j = 0; j < 8; ++j) bv[j] = wsh[e][tx * 8 + j];
#pragma unroll
        for (int i = 0; i < 4; ++i)
#pragma unroll
            for (int j = 0; j < 8; ++j)
                acc[i][j] = fmaf(a[i], bv[j], acc[i][j]);
    }
#pragma unroll
    for (int i = 0; i < 4; ++i)
#pragma unroll
        for (int j = 0; j < 8; ++j)
            so[tx * 8 + j][ty * 4 + i] = (_Float16)acc[i][j];
    __syncthreads();
#pragma unroll
    for (int q = tid; q < 1024; q += 256) {
        const int c_local = q >> 3, co = (q & 7) * 8;
        *(half8_t*)(a2tT + (long)b * 262144 + (long)(ct * 128 + c_local) * 512
                    + h * 64 + co) = *(const half8_t*)&so[c_local][co];
    }
}

extern "C" void kernel_launch(void* const* d_in, const int* in_sizes, int n_in,
                              void* d_out, int out_size, void* d_ws, size_t ws_size,
                              hipStream_t stream)
{
    const float* x      = (const float*)d_in[0];   // (8,512,4096)
    const float* w_qkv  = (const float*)d_in[1];   // (512,1536)
    const float* w_out  = (const float*)d_in[2];   // (512,512)
    const float* b_out  = (const float*)d_in[3];   // (512,)
    float* out = (float*)d_out;                    // (8,512,4096)

    char* wsb = (char*)d_ws;                       // ~122 MB total
    _Float16* kv   = (_Float16*)(wsb);             // 64 MB  [b][f][l]
    _Float16* xT   = (_Float16*)(wsb + 67108864);  // 32 MB  [b][l][c]
    _Float16* wkvT = (_Float16*)(wsb + 100663296); // 1 MB   [f][c]
    _Float16* wqs  = (_Float16*)(wsb + 101711872); // 0.5 MB [c'][g]
    _Float16* a2tT = (_Float16*)(wsb + 102236160); // 4 MB   [b][c][g]
    _Float16* mf   = (_Float16*)(wsb + 106430464); // 4 MB   [b][c][c']
    float*    ctxP = (float*)   (wsb + 110624768); // 16 MB  [s][bh][e*64+d]

    // xT = transpose+cvt(x): src rows c=512, cols l=4096
    transpose_cvt<<<dim3(64, 8, 8), 256, 0, stream>>>(
        x, 4096, 2097152L, xT, 512, 2097152L);
    // wkvT[f][c]: src rows c=512 (ld 1536, offset 512), cols f=1024
    transpose_cvt<<<dim3(16, 8, 1), 256, 0, stream>>>(
        w_qkv + 512, 1536, 0L, wkvT, 512, 0L);
    // wqs[c'][g] = SCALE * w_qkv[c'][g]
    scale_wq_kernel<<<dim3(512), 256, 0, stream>>>(w_qkv, wqs);

    // K1: kv[b][f][l] = sum_c wkvT[f][c] * xT[b][l][c]   (M=1024,N=4096,K=512)
    gemm256<_Float16><<<dim3(16, 4, 8), 512, 0, stream>>>(
        wkvT, 0L, 512, xT, 2097152L, kv, 4096, 4194304L, nullptr);

    // K2: softmax over L on the k half
    softmax_rows_h<<<dim3(4096), 256, 0, stream>>>(kv);

    // K3: context partials via MFMA
    context_mfma<<<dim3(CSPLIT, 64), 256, 0, stream>>>(kv, ctxP);

    // K4a: a2tT (reduces the CSPLIT partials on load)
    a2t_kernel<<<dim3(4, 8, 8), 256, 0, stream>>>(ctxP, w_out, a2tT);

    // K4m: mf[b][c][c'] = sum_g a2tT[b][c][g] * wqs[c'][g]   (= M^T, f16)
    gemm_mfma<_Float16><<<dim3(4, 4, 8), 256, 0, stream>>>(
        a2tT, 262144L, 512, wqs, 0L, mf, 512, 262144L, nullptr);

    // K5: out[b][c][l] = sum_c' mf[b][c][c'] * xT[b][l][c'] + b_out[c]
    //     (M=512,N=4096,K=512)
    gemm256<float><<<dim3(16, 2, 8), 512, 0, stream>>>(
        mf, 262144L, 512, xT, 2097152L, out, 4096, 2097152L, b_out);
}

// Round 4
// 258.987 us; speedup vs baseline: 1.1039x; 1.0110x over previous
//
#include <hip/hip_runtime.h>

// LinearAttention, fp16-MFMA restructuring (round 7).
//   xT   = transpose+cvt(x)          [b][l][c] f16   (B-operand for K1,K5)
//   kv   = wkvT @ xT^T  (MFMA)       [b][f][l] f16, f<512:k, f>=512:v
//   k    = softmax_L(k)              in place, f16
//   ctxP = v k^T partials (MFMA, K split 16)  [s][bh][e*64+d] f32
//   a2tT = (sum_s ctxP . w_out)^T    [b][c][g] f16  (k-fast for M-build)
//   Mf   = a2tT @ wqs^T (MFMA)       [b][c][c'] f16 = A-operand of K5
//   out  = Mf @ xT^T + b_out (MFMA, fp32 out)
// Round-7: gemm256 K-loop rebuilt as the m201 8-phase template (4 phases per
// K-tile, each {STG 1 half-tile; ds_read subtile; bar; lgkm0; 16 MFMA; bar}),
// counted vmcnt(8)/vmcnt(6) twice per tile (derived per-wave accounting,
// 3-4 half-tiles in flight, never drain-0 in loop), exact tail:
// loop t<=T-3, stage B1/A1(T-1), vmcnt(0)+bar, 2 barrier-free drain tiles.
// Calibration from round-6 counters: MFMA pipe time = 2048 cyc/SIMD/K-tile;
// wall was 7500 (MfmaUtil 25% == 2048/7500); template wall 3300 (62%).

typedef _Float16 half2_t __attribute__((ext_vector_type(2)));
typedef _Float16 half4_t __attribute__((ext_vector_type(4)));
typedef _Float16 half8_t __attribute__((ext_vector_type(8)));
typedef float    floatx4 __attribute__((ext_vector_type(4)));

#define SCALE_ 0.125f
#define CSPLIT 16

typedef __attribute__((address_space(3))) _Float16 lds_half;

__device__ __forceinline__ void async_lds16(const _Float16* g, _Float16* l) {
    __builtin_amdgcn_global_load_lds(
        (const __attribute__((address_space(1))) void*)g,
        (__attribute__((address_space(3))) void*)l,
        16, 0, 0);
}

__device__ __forceinline__ half8_t lds_read16(const lds_half* p) {
    half8_t r;
    asm volatile("ds_read_b128 %0, %1" : "=v"(r) : "v"(p));
    return r;
}

#define FENCE() asm volatile("" ::: "memory")
#define BAR()  do { FENCE(); __builtin_amdgcn_s_barrier(); FENCE(); } while (0)
#define VMW8() asm volatile("s_waitcnt vmcnt(8)" ::: "memory")
#define VMW6() asm volatile("s_waitcnt vmcnt(6)" ::: "memory")
#define VMW4() asm volatile("s_waitcnt vmcnt(4)" ::: "memory")
#define VMW0() asm volatile("s_waitcnt vmcnt(0)" ::: "memory")
#define LGKM0_SB() do { \
    asm volatile("s_waitcnt lgkmcnt(0)" ::: "memory"); \
    __builtin_amdgcn_sched_barrier(0); \
} while (0)

// ---------------- 256x256 MFMA GEMM, 8-phase counted-vmcnt pipeline --------
// C[m][n] = sum_k A[m][k]*B[n][k] (+bias[m]).  A:[M][K] k-fast, B:[N][K]
// k-fast, C:[M][N].  Requires M%256==0, N%256==0, K%64==0, K>=256,
// grid blocks %8==0.
template <typename OutT>
__global__ __launch_bounds__(512, 2)
void gemm256(const _Float16* __restrict__ A, long aBatch, int K,
             const _Float16* __restrict__ B, long bBatch,
             OutT* __restrict__ C, int ldc, long cBatch,
             const float* __restrict__ bias)
{
    // 128 KB: [dbuf(2)][A=0/B=1][half(2)][128*64 f16 = 16KB]
    __shared__ _Float16 smem[65536];
    const int tid  = threadIdx.x;
    const int lane = tid & 63;
    const int wave = tid >> 6;
    const int wm2 = wave >> 2;          // 0..1 (M split)
    const int wn4 = wave & 3;           // 0..3 (N split)

    // T1: XCD swizzle (bijective: nwg % 8 == 0 for all our launches).
    const int nx = gridDim.x, ny = gridDim.y;
    const int nwg = nx * ny * gridDim.z;
    const int bid = blockIdx.x + nx * (blockIdx.y + ny * blockIdx.z);
    const int per = nwg >> 3;
    const int wg  = (bid & 7) * per + (bid >> 3);
    const int yb = wg % ny;
    const int xb = (wg / ny) % nx;
    const int zb = wg / (ny * nx);

    const int m0 = yb * 256;
    const int n0 = xb * 256;
    const long bz = zb;

    // ---- staging map: thread -> (row = tid>>3 (+64/128), phys granule tid&7)
    // inverse-swizzled SOURCE: physical granule g at row r holds logical
    // granule g^(r&7)  (rule #21: linear LDS dest, pre-swizzled global src)
    const int srow = tid >> 3;
    const int sxor = (((tid & 7) ^ (srow & 7)) << 3);   // elems
    const _Float16* pA = A + bz * aBatch + (long)(m0 + srow) * K + sxor;
    const _Float16* pB = B + bz * bBatch + (long)(n0 + srow) * K + sxor;
    _Float16* ldst = &smem[tid * 8];

    // stage one half-tile (128 rows x 64 cols) of K-tile t_: 2 x gload_lds16
    // (2 VMEM instructions per WAVE -> vmcnt counts below are 2/half-tile)
#define STG(t_, ab_, h_, pG_) do { \
    async_lds16((pG_) + (long)((h_) * 128) * K + (t_) * 64, \
                ldst + ((t_) & 1) * 32768 + (ab_) * 16384 + (h_) * 8192); \
    async_lds16((pG_) + (long)((h_) * 128 + 64) * K + (t_) * 64, \
                ldst + ((t_) & 1) * 32768 + (ab_) * 16384 + (h_) * 8192 + 4096); \
} while (0)

    // ---- fragment read offsets (swizzled ds_read side), element units
    const int fm  = lane & 15;
    const int fkg = lane >> 4;          // 0..3
    int aRow[4], bRow[2], gxo[2];
#pragma unroll
    for (int i = 0; i < 4; ++i) aRow[i] = (wm2 * 64 + i * 16 + fm) << 6;
#pragma unroll
    for (int j = 0; j < 2; ++j) bRow[j] = (wn4 * 32 + j * 16 + fm) << 6;
#pragma unroll
    for (int k = 0; k < 2; ++k) gxo[k] = (((k * 4 + fkg) ^ (fm & 7)) << 3);

    const lds_half* sm3 = (const lds_half*)&smem[0];

    floatx4 acc[8][4];
#pragma unroll
    for (int i = 0; i < 8; ++i)
#pragma unroll
        for (int j = 0; j < 4; ++j) acc[i][j] = (floatx4)0.0f;

    half8_t aF[8], bF0[4], bF1[4];

#define LDA_(d_, qm_) do { \
    const lds_half* base_ = sm3 + (d_) * 32768 + (qm_) * 8192; \
    _Pragma("unroll") \
    for (int i = 0; i < 4; ++i) \
    _Pragma("unroll") \
        for (int k = 0; k < 2; ++k) \
            aF[i * 2 + k] = lds_read16(base_ + aRow[i] + gxo[k]); \
} while (0)

#define LDB_(d_, qn_, BF) do { \
    const lds_half* base_ = sm3 + (d_) * 32768 + 16384 + (qn_) * 8192; \
    _Pragma("unroll") \
    for (int j = 0; j < 2; ++j) \
    _Pragma("unroll") \
        for (int k = 0; k < 2; ++k) \
            BF[j * 2 + k] = lds_read16(base_ + bRow[j] + gxo[k]); \
} while (0)

#define MFMA16(qm_, qn_, BF) do { \
    __builtin_amdgcn_s_setprio(1); \
    _Pragma("unroll") \
    for (int i = 0; i < 4; ++i) \
    _Pragma("unroll") \
        for (int j = 0; j < 2; ++j) \
    _Pragma("unroll") \
            for (int k = 0; k < 2; ++k) \
                acc[(qm_) * 4 + i][(qn_) * 2 + j] = \
                    __builtin_amdgcn_mfma_f32_16x16x32_f16( \
                        aF[i * 2 + k], BF[j * 2 + k], \
                        acc[(qm_) * 4 + i][(qn_) * 2 + j], 0, 0, 0); \
    __builtin_amdgcn_s_setprio(0); \
} while (0)

    // prologue: stage tile0 fully + A0,B0 of tile1 (12 instrs/wave).
    // vmcnt(4) -> tile0 landed, A0B0(1) in flight.
    STG(0, 0, 0, pA); STG(0, 1, 0, pB);
    STG(0, 1, 1, pB); STG(0, 0, 1, pA);
    STG(1, 0, 0, pA); STG(1, 1, 0, pB);
    VMW4(); BAR();

    const int T = K >> 6;               // T >= 4 assumed (K >= 256)
    // Main loop: iteration t stages B1(t+1),A1(t+1),A0(t+2),B0(t+2).
    // Wait accounting (per wave, 2 instrs/half-tile), steady state:
    //  end phB: outstanding {A0(t+1),B0(t+1),B1(t+1),A1(t+1),A1(t)} ->
    //           vmcnt(8) drains A1(t) (needed phC).
    //  end phD: outstanding {A1(t+1),A0(t+2),B0(t+2),B1(t+1)...} = 12 ->
    //           vmcnt(6) leaves {A1(t+1),A0(t+2),B0(t+2)}; A0/B0/B1(t+1)
    //           landed for next tile's phA/phB.
    for (int t = 0; t <= T - 3; ++t) {
        const int d = t & 1;
        // ---- phase A: quadrant (0,0)
        STG(t + 1, 1, 1, pB);           // B1(t+1) -> buf[(t+1)&1]
        LDA_(d, 0);
        LDB_(d, 0, bF0);
        BAR();
        LGKM0_SB();
        MFMA16(0, 0, bF0);
        BAR();
        // ---- phase B: quadrant (0,1)
        STG(t + 1, 0, 1, pA);           // A1(t+1)
        LDB_(d, 1, bF1);
        BAR();
        LGKM0_SB();
        MFMA16(0, 1, bF1);
        VMW8();
        BAR();
        // ---- phase C: quadrant (1,1)
        STG(t + 2, 0, 0, pA);           // A0(t+2) -> buf[t&1] (A0 reads done phA)
        LDA_(d, 1);
        BAR();
        LGKM0_SB();
        MFMA16(1, 1, bF1);
        BAR();
        // ---- phase D: quadrant (1,0)  (all frags in regs)
        STG(t + 2, 1, 0, pB);           // B0(t+2) (B0 reads done phA)
        MFMA16(1, 0, bF0);
        VMW6();
        BAR();
    }

    // tail: stage the two half-tiles the loop never issued, drain, then
    // compute tiles T-2, T-1 barrier-free (no more LDS writes).
    STG(T - 1, 1, 1, pB);               // B1(T-1)
    STG(T - 1, 0, 1, pA);               // A1(T-1)
    VMW0(); BAR();
#pragma unroll
    for (int u = 0; u < 2; ++u) {
        const int t = T - 2 + u;
        const int d = t & 1;
        LDA_(d, 0); LDB_(d, 0, bF0);
        LGKM0_SB();
        MFMA16(0, 0, bF0);
        LDB_(d, 1, bF1);
        LGKM0_SB();
        MFMA16(0, 1, bF1);
        LDA_(d, 1);
        LGKM0_SB();
        MFMA16(1, 1, bF1);
        MFMA16(1, 0, bF0);
    }
#undef STG
#undef LDA_
#undef LDB_
#undef MFMA16

    // C/D layout: n = lane&15, m = (lane>>4)*4 + reg   [m89/m91-verified]
    const int em = (lane >> 4) * 4;
    const int en = lane & 15;
    OutT* Cb = C + bz * cBatch;
#pragma unroll
    for (int qm = 0; qm < 2; ++qm)
#pragma unroll
        for (int i = 0; i < 4; ++i)
#pragma unroll
            for (int r = 0; r < 4; ++r) {
                const int m = m0 + qm * 128 + wm2 * 64 + i * 16 + em + r;
                const float bi = bias ? bias[m] : 0.0f;
#pragma unroll
                for (int qn = 0; qn < 2; ++qn)
#pragma unroll
                    for (int j = 0; j < 2; ++j) {
                        const int n = n0 + qn * 128 + wn4 * 32 + j * 16 + en;
                        Cb[(long)m * ldc + n] =
                            (OutT)(acc[qm * 4 + i][qn * 2 + j][r] + bi);
                    }
            }
}

// ---------------- MFMA GEMM (128x128, round-3 proven form) ------------------
// Used only for K4m (small). A:[M][K] k-fast, B:[N][K] k-fast, C:[M][N].
template <typename OutT>
__global__ __launch_bounds__(256)
void gemm_mfma(const _Float16* __restrict__ A, long aBatch, int K,
               const _Float16* __restrict__ B, long bBatch,
               OutT* __restrict__ C, int ldc, long cBatch,
               const float* __restrict__ bias)
{
    __shared__ _Float16 As[128 * 32];
    __shared__ _Float16 Bs[128 * 32];
    const int tid  = threadIdx.x;
    const int lane = tid & 63;
    const int wave = tid >> 6;
    const int m0 = blockIdx.y * 128;
    const int n0 = blockIdx.x * 128;
    const long bz = blockIdx.z;
    const _Float16* Ag = A + bz * aBatch + (long)m0 * K;
    const _Float16* Bg = B + bz * bBatch + (long)n0 * K;

    const int sr = tid >> 2;
    const int sc = (tid & 3) * 8;

    const int wm = (wave & 1) * 64;
    const int wn = (wave >> 1) * 64;
    const int fm = lane & 15;
    const int fk = (lane >> 4) * 8;

    floatx4 acc[4][4];
#pragma unroll
    for (int i = 0; i < 4; ++i)
#pragma unroll
        for (int j = 0; j < 4; ++j) acc[i][j] = (floatx4)0.0f;

    for (int k0 = 0; k0 < K; k0 += 32) {
        __syncthreads();
        async_lds16(Ag + (long)sr * K + k0 + sc,        &As[tid * 8]);
        async_lds16(Ag + (long)(sr + 64) * K + k0 + sc, &As[2048 + tid * 8]);
        async_lds16(Bg + (long)sr * K + k0 + sc,        &Bs[tid * 8]);
        async_lds16(Bg + (long)(sr + 64) * K + k0 + sc, &Bs[2048 + tid * 8]);
        __syncthreads();

        half8_t a[4], b[4];
#pragma unroll
        for (int i = 0; i < 4; ++i)
            a[i] = *(const half8_t*)&As[(wm + i * 16 + fm) * 32 + fk];
#pragma unroll
        for (int j = 0; j < 4; ++j)
            b[j] = *(const half8_t*)&Bs[(wn + j * 16 + fm) * 32 + fk];
#pragma unroll
        for (int i = 0; i < 4; ++i)
#pragma unroll
            for (int j = 0; j < 4; ++j)
                acc[i][j] = __builtin_amdgcn_mfma_f32_16x16x32_f16(
                    a[i], b[j], acc[i][j], 0, 0, 0);
    }

    const int em = (lane >> 4) * 4;
    const int en = lane & 15;
    OutT* Cb = C + bz * cBatch;
#pragma unroll
    for (int i = 0; i < 4; ++i) {
#pragma unroll
        for (int r = 0; r < 4; ++r) {
            const int m = m0 + wm + i * 16 + em + r;
            const float bi = bias ? bias[m] : 0.0f;
#pragma unroll
            for (int j = 0; j < 4; ++j) {
                const int n = n0 + wn + j * 16 + en;
                Cb[(long)m * ldc + n] = (OutT)(acc[i][j][r] + bi);
            }
        }
    }
}

// ---------------- context via MFMA: ctxP[s][bh][e*64+d] --------------------
__global__ __launch_bounds__(256)
void context_mfma(const _Float16* __restrict__ kv, float* __restrict__ ctxP)
{
    const int bh = blockIdx.y;             // 0..63
    const int b = bh >> 3, h = bh & 7;
    const int l0 = blockIdx.x * (4096 / CSPLIT);   // 256-wide l slab
    const _Float16* vbase = kv + (long)b * 4194304 + (long)(512 + h * 64) * 4096;
    const _Float16* kbase = kv + (long)b * 4194304 + (long)(h * 64) * 4096;

    __shared__ _Float16 As[64 * 32];   // v tile [e][32]
    __shared__ _Float16 Bs[64 * 32];   // k tile [d][32]
    const int tid  = threadIdx.x;
    const int lane = tid & 63;
    const int wave = tid >> 6;
    const int sr = tid >> 2;
    const int sc = (tid & 3) * 8;
    const int wm = (wave & 1) * 32;
    const int wn = (wave >> 1) * 32;
    const int fm = lane & 15;
    const int fk = (lane >> 4) * 8;

    floatx4 acc[2][2];
#pragma unroll
    for (int i = 0; i < 2; ++i)
#pragma unroll
        for (int j = 0; j < 2; ++j) acc[i][j] = (floatx4)0.0f;

    for (int k0 = 0; k0 < 4096 / CSPLIT; k0 += 32) {
        __syncthreads();
        async_lds16(vbase + (long)sr * 4096 + l0 + k0 + sc, &As[tid * 8]);
        async_lds16(kbase + (long)sr * 4096 + l0 + k0 + sc, &Bs[tid * 8]);
        __syncthreads();

        half8_t a[2], b2[2];
#pragma unroll
        for (int i = 0; i < 2; ++i)
            a[i] = *(const half8_t*)&As[(wm + i * 16 + fm) * 32 + fk];
#pragma unroll
        for (int j = 0; j < 2; ++j)
            b2[j] = *(const half8_t*)&Bs[(wn + j * 16 + fm) * 32 + fk];
#pragma unroll
        for (int i = 0; i < 2; ++i)
#pragma unroll
            for (int j = 0; j < 2; ++j)
                acc[i][j] = __builtin_amdgcn_mfma_f32_16x16x32_f16(
                    a[i], b2[j], acc[i][j], 0, 0, 0);
    }

    const int em = (lane >> 4) * 4;
    const int en = lane & 15;
    float* base = ctxP + ((long)blockIdx.x * 64 + bh) * 4096;
#pragma unroll
    for (int i = 0; i < 2; ++i)
#pragma unroll
        for (int r = 0; r < 4; ++r)
#pragma unroll
            for (int j = 0; j < 2; ++j)
                base[(wm + i * 16 + em + r) * 64 + wn + j * 16 + en] = acc[i][j][r];
}

// ---------------- transpose + fp32->fp16 convert ---------------------------
__global__ __launch_bounds__(256)
void transpose_cvt(const float* __restrict__ src, int ld_s, long sB,
                   _Float16* __restrict__ dst, int ld_d, long dB)
{
    __shared__ float tile[64][65];
    const int c0 = blockIdx.x * 64;
    const int r0 = blockIdx.y * 64;
    const float* S = src + (long)blockIdx.z * sB;
    _Float16* D = dst + (long)blockIdx.z * dB;
    const int t = threadIdx.x;
    const int lr = t >> 4;
    const int lc = (t & 15) * 4;
#pragma unroll
    for (int i = 0; i < 4; ++i) {
        const float4 v = *(const float4*)(S + (long)(r0 + lr + 16 * i) * ld_s + c0 + lc);
        tile[lr + 16 * i][lc + 0] = v.x;
        tile[lr + 16 * i][lc + 1] = v.y;
        tile[lr + 16 * i][lc + 2] = v.z;
        tile[lr + 16 * i][lc + 3] = v.w;
    }
    __syncthreads();
    const int rl = (t & 15) * 4;
    const int cl = t >> 4;
#pragma unroll
    for (int i = 0; i < 4; ++i) {
        const int c = cl + 16 * i;
        half4_t o;
        o[0] = (_Float16)tile[rl + 0][c];
        o[1] = (_Float16)tile[rl + 1][c];
        o[2] = (_Float16)tile[rl + 2][c];
        o[3] = (_Float16)tile[rl + 3][c];
        *(half4_t*)(D + (long)(c0 + c) * ld_d + r0 + rl) = o;
    }
}

// ---------------- wqs[c'][g] = SCALE * w_qkv[c'][g], f16 -------------------
__global__ __launch_bounds__(256)
void scale_wq_kernel(const float* __restrict__ w_qkv, _Float16* __restrict__ wqs)
{
    const int c = blockIdx.x;
    const int t = threadIdx.x;
    const float2 v = *(const float2*)(w_qkv + (long)c * 1536 + t * 2);
    half2_t o;
    o[0] = (_Float16)(v.x * SCALE_);
    o[1] = (_Float16)(v.y * SCALE_);
    *(half2_t*)(wqs + (long)c * 512 + t * 2) = o;
}

// ---------------- softmax over L per (b, f<512) row, f16 in place ----------
__global__ __launch_bounds__(256)
void softmax_rows_h(_Float16* __restrict__ kv)
{
    const int row = blockIdx.x;            // 0..4095
    const int b = row >> 9, f = row & 511;
    _Float16* p = kv + (long)b * 4194304 + (long)f * 4096;
    const int tid = threadIdx.x;

    half8_t h0 = *(const half8_t*)(p + tid * 16);
    half8_t h1 = *(const half8_t*)(p + tid * 16 + 8);
    float v[16];
#pragma unroll
    for (int i = 0; i < 8; ++i) { v[i] = (float)h0[i]; v[8 + i] = (float)h1[i]; }

    float mx = -3.4e38f;
#pragma unroll
    for (int i = 0; i < 16; ++i) mx = fmaxf(mx, v[i]);
#pragma unroll
    for (int off = 32; off > 0; off >>= 1)
        mx = fmaxf(mx, __shfl_down(mx, off));

    __shared__ float red[8];
    if ((tid & 63) == 0) red[tid >> 6] = mx;
    __syncthreads();
    mx = fmaxf(fmaxf(red[0], red[1]), fmaxf(red[2], red[3]));

    float s = 0.0f;
#pragma unroll
    for (int i = 0; i < 16; ++i) { v[i] = __expf(v[i] - mx); s += v[i]; }
#pragma unroll
    for (int off = 32; off > 0; off >>= 1)
        s += __shfl_down(s, off);
    if ((tid & 63) == 0) red[4 + (tid >> 6)] = s;
    __syncthreads();
    const float inv = 1.0f / (red[4] + red[5] + red[6] + red[7]);

#pragma unroll
    for (int i = 0; i < 8; ++i) {
        h0[i] = (_Float16)(v[i] * inv);
        h1[i] = (_Float16)(v[8 + i] * inv);
    }
    *(half8_t*)(p + tid * 16) = h0;
    *(half8_t*)(p + tid * 16 + 8) = h1;
}

// ---- a2tT[b][c][g] = (sum_e (sum_s ctxP)[e][d] w_out[(h,e),c])^T, f16 -----
__global__ __launch_bounds__(256)
void a2t_kernel(const float* __restrict__ ctxP, const float* __restrict__ w_out,
                _Float16* __restrict__ a2tT)
{
    const int ct = blockIdx.x, h = blockIdx.y, b = blockIdx.z;
    __shared__ float cs[64][64];      // cs[e][d]
    __shared__ float wsh[64][128];    // wsh[e][c]
    __shared__ _Float16 so[128][64];  // so[c_local][d]
    const int tid = threadIdx.x;
    {
        const int lr = tid >> 4, lc4 = (tid & 15) * 4;
        floatx4 accv[4];
#pragma unroll
        for (int i = 0; i < 4; ++i) accv[i] = (floatx4)0.0f;
        for (int s = 0; s < CSPLIT; ++s) {
            const float* cbase = ctxP + ((long)s * 64 + b * 8 + h) * 4096;
#pragma unroll
            for (int i = 0; i < 4; ++i)
                accv[i] += *(const floatx4*)(cbase + (lr + 16 * i) * 64 + lc4);
        }
#pragma unroll
        for (int i = 0; i < 4; ++i)
            *(floatx4*)&cs[lr + 16 * i][lc4] = accv[i];

        const float* wbase = w_out + (long)(h * 64) * 512 + ct * 128;
        const int wr = tid >> 5, wc4 = (tid & 31) * 4;
#pragma unroll
        for (int i = 0; i < 8; ++i) {
            const int e = wr + 8 * i;
            *(float4*)&wsh[e][wc4] = *(const float4*)(wbase + (long)e * 512 + wc4);
        }
    }
    __syncthreads();
    const int tx = tid & 15, ty = tid >> 4;
    float acc[4][8] = {};
    for (int e = 0; e < 64; ++e) {
        float a[4], bv[8];
#pragma unroll
        for (int i = 0; i < 4; ++i) a[i] = cs[e][ty * 4 + i];
#pragma unroll
        for (int j = 0; j < 8; ++j) bv[j] = wsh[e][tx * 8 + j];
#pragma unroll
        for (int i = 0; i < 4; ++i)
#pragma unroll
            for (int j = 0; j < 8; ++j)
                acc[i][j] = fmaf(a[i], bv[j], acc[i][j]);
    }
#pragma unroll
    for (int i = 0; i < 4; ++i)
#pragma unroll
        for (int j = 0; j < 8; ++j)
            so[tx * 8 + j][ty * 4 + i] = (_Float16)acc[i][j];
    __syncthreads();
#pragma unroll
    for (int q = tid; q < 1024; q += 256) {
        const int c_local = q >> 3, co = (q & 7) * 8;
        *(half8_t*)(a2tT + (long)b * 262144 + (long)(ct * 128 + c_local) * 512
                    + h * 64 + co) = *(const half8_t*)&so[c_local][co];
    }
}

extern "C" void kernel_launch(void* const* d_in, const int* in_sizes, int n_in,
                              void* d_out, int out_size, void* d_ws, size_t ws_size,
                              hipStream_t stream)
{
    const float* x      = (const float*)d_in[0];   // (8,512,4096)
    const float* w_qkv  = (const float*)d_in[1];   // (512,1536)
    const float* w_out  = (const float*)d_in[2];   // (512,512)
    const float* b_out  = (const float*)d_in[3];   // (512,)
    float* out = (float*)d_out;                    // (8,512,4096)

    char* wsb = (char*)d_ws;                       // ~122 MB total
    _Float16* kv   = (_Float16*)(wsb);             // 64 MB  [b][f][l]
    _Float16* xT   = (_Float16*)(wsb + 67108864);  // 32 MB  [b][l][c]
    _Float16* wkvT = (_Float16*)(wsb + 100663296); // 1 MB   [f][c]
    _Float16* wqs  = (_Float16*)(wsb + 101711872); // 0.5 MB [c'][g]
    _Float16* a2tT = (_Float16*)(wsb + 102236160); // 4 MB   [b][c][g]
    _Float16* mf   = (_Float16*)(wsb + 106430464); // 4 MB   [b][c][c']
    float*    ctxP = (float*)   (wsb + 110624768); // 16 MB  [s][bh][e*64+d]

    // xT = transpose+cvt(x): src rows c=512, cols l=4096
    transpose_cvt<<<dim3(64, 8, 8), 256, 0, stream>>>(
        x, 4096, 2097152L, xT, 512, 2097152L);
    // wkvT[f][c]: src rows c=512 (ld 1536, offset 512), cols f=1024
    transpose_cvt<<<dim3(16, 8, 1), 256, 0, stream>>>(
        w_qkv + 512, 1536, 0L, wkvT, 512, 0L);
    // wqs[c'][g] = SCALE * w_qkv[c'][g]
    scale_wq_kernel<<<dim3(512), 256, 0, stream>>>(w_qkv, wqs);

    // K1: kv[b][f][l] = sum_c wkvT[f][c] * xT[b][l][c]   (M=1024,N=4096,K=512)
    gemm256<_Float16><<<dim3(16, 4, 8), 512, 0, stream>>>(
        wkvT, 0L, 512, xT, 2097152L, kv, 4096, 4194304L, nullptr);

    // K2: softmax over L on the k half
    softmax_rows_h<<<dim3(4096), 256, 0, stream>>>(kv);

    // K3: context partials via MFMA
    context_mfma<<<dim3(CSPLIT, 64), 256, 0, stream>>>(kv, ctxP);

    // K4a: a2tT (reduces the CSPLIT partials on load)
    a2t_kernel<<<dim3(4, 8, 8), 256, 0, stream>>>(ctxP, w_out, a2tT);

    // K4m: mf[b][c][c'] = sum_g a2tT[b][c][g] * wqs[c'][g]   (= M^T, f16)
    gemm_mfma<_Float16><<<dim3(4, 4, 8), 256, 0, stream>>>(
        a2tT, 262144L, 512, wqs, 0L, mf, 512, 262144L, nullptr);

    // K5: out[b][c][l] = sum_c' mf[b][c][c'] * xT[b][l][c'] + b_out[c]
    //     (M=512,N=4096,K=512)
    gemm256<float><<<dim3(16, 2, 8), 512, 0, stream>>>(
        mf, 262144L, 512, xT, 2097152L, out, 4096, 2097152L, b_out);
}